// Round 4
// baseline (17122.778 us; speedup 1.0000x reference)
//
#include <hip/hip_runtime.h>
#include <stdint.h>

typedef unsigned short u16;
typedef unsigned int   u32;
typedef unsigned long long u64;
typedef short bf16x8 __attribute__((ext_vector_type(8)));
typedef float f32x4  __attribute__((ext_vector_type(4)));

static_assert(sizeof(bf16x8) == 16, "bf16x8 must be 16B");

#define LOG2E 1.4426950408889634f
#define TCH 32   // timesteps per chunk

__device__ __forceinline__ float bf2f(u16 u) { return __builtin_bit_cast(float, ((u32)u) << 16); }
__device__ __forceinline__ u16 f2bf(float f) {
  u32 x = __builtin_bit_cast(u32, f);
  return (u16)((x + 0x7fffu + ((x >> 16) & 1u)) >> 16);   // RNE, inputs are tame (no NaN)
}
__device__ __forceinline__ float sigm(float x) {
  return __builtin_amdgcn_rcpf(1.f + __builtin_amdgcn_exp2f(-LOG2E * x));
}
__device__ __forceinline__ float tanh_(float x) {
  return 1.f - 2.f * __builtin_amdgcn_rcpf(1.f + __builtin_amdgcn_exp2f(2.f * LOG2E * x));
}
__device__ __forceinline__ bf16x8 cvt8(const float* p) {
  bf16x8 r;
  #pragma unroll
  for (int j = 0; j < 8; ++j) r[j] = (short)f2bf(p[j]);
  return r;
}

// ---- coherent (agent-scope, MALL-level) access helpers ----
union U16x8 { u64 q[2]; bf16x8 v; };
__device__ __forceinline__ bf16x8 ldh16(const u16* p) {   // 16B coherent load (2x u64)
  U16x8 u;
  u.q[0] = __hip_atomic_load((const u64*)p,     __ATOMIC_RELAXED, __HIP_MEMORY_SCOPE_AGENT);
  u.q[1] = __hip_atomic_load((const u64*)p + 1, __ATOMIC_RELAXED, __HIP_MEMORY_SCOPE_AGENT);
  return u.v;
}
__device__ __forceinline__ void sth(u16* p, u16 v) {      // 2B coherent store
  __hip_atomic_store(p, v, __ATOMIC_RELAXED, __HIP_MEMORY_SCOPE_AGENT);
}

// ---------------- prep kernels ----------------
__global__ void k_cvt(const float* __restrict__ src, u16* __restrict__ dst, int n) {
  int i = blockIdx.x * blockDim.x + threadIdx.x;
  int st = gridDim.x * blockDim.x;
  for (; i < n; i += st) dst[i] = f2bf(src[i]);
}

__global__ void k_bias(const float* __restrict__ bi0, const float* __restrict__ bh0,
                       const float* __restrict__ bi, const float* __restrict__ bh,
                       float* __restrict__ out) {
  int i = blockIdx.x * blockDim.x + threadIdx.x;
  if (i < 4096) out[i] = bi0[i] + bh0[i];
  else if (i < 20480) out[i] = bi[i - 4096] + bh[i - 4096];
}

// ---------------- input GEMM over one time-chunk ----------------
__global__ __launch_bounds__(256) void k_gemm(
    const u16* __restrict__ X, const float* __restrict__ emb, const int* __restrict__ tok,
    const u16* __restrict__ Wi, const float* __restrict__ bias,
    u16* __restrict__ gx, int K, int t0)
{
  int d   = blockIdx.x >> 4;     // direction
  int nt0 = blockIdx.x & 15;     // N tile (128 gates)
  int tt  = blockIdx.y;          // timestep within chunk
  int t   = t0 + tt;
  __shared__ u16 As[128 * 64];
  __shared__ u16 Bs[128 * 64];
  __shared__ int s_tok[128];
  int tid = threadIdx.x, lane = tid & 63, w = tid >> 6;
  int wm = w & 1, wn = w >> 1;
  if (tok && tid < 128) s_tok[tid] = tok[t * 128 + tid];
  __syncthreads();

  const u16* Bbase = Wi + ((size_t)d * 2048 + nt0 * 128) * K;
  f32x4 acc[4][4];
  #pragma unroll
  for (int a = 0; a < 4; ++a)
    #pragma unroll
    for (int b = 0; b < 4; ++b) acc[a][b] = f32x4{0.f, 0.f, 0.f, 0.f};

  int nkt = K >> 6;  // K-tiles of 64
  for (int kt = 0; kt < nkt; ++kt) {
    #pragma unroll
    for (int i = 0; i < 4; ++i) {
      int s = tid + i * 256;              // slot 0..1023
      int row = s >> 3, c = s & 7;
      int cs = c ^ (row & 7);             // XOR-swizzle kills ds_read bank conflicts
      bf16x8 va;
      if (tok) {
        va = cvt8(emb + (size_t)s_tok[row] * 320 + kt * 64 + c * 8);
      } else {
        va = *(const bf16x8*)(X + ((size_t)t * 128 + row) * K + kt * 64 + c * 8);
      }
      bf16x8 vb = *(const bf16x8*)(Bbase + (size_t)row * K + kt * 64 + c * 8);
      *(bf16x8*)(&As[(row * 8 + cs) * 8]) = va;
      *(bf16x8*)(&Bs[(row * 8 + cs) * 8]) = vb;
    }
    __syncthreads();
    #pragma unroll
    for (int kk2 = 0; kk2 < 2; ++kk2) {
      int cl = kk2 * 4 + (lane >> 4);
      bf16x8 af[4], bfr[4];
      #pragma unroll
      for (int mt = 0; mt < 4; ++mt) {
        int row = wm * 64 + mt * 16 + (lane & 15);
        af[mt] = *(const bf16x8*)(&As[(row * 8 + (cl ^ (row & 7))) * 8]);
      }
      #pragma unroll
      for (int nt = 0; nt < 4; ++nt) {
        int row = wn * 64 + nt * 16 + (lane & 15);
        bfr[nt] = *(const bf16x8*)(&Bs[(row * 8 + (cl ^ (row & 7))) * 8]);
      }
      #pragma unroll
      for (int mt = 0; mt < 4; ++mt)
        #pragma unroll
        for (int nt = 0; nt < 4; ++nt)
          acc[mt][nt] = __builtin_amdgcn_mfma_f32_16x16x32_bf16(af[mt], bfr[nt], acc[mt][nt], 0, 0, 0);
    }
    __syncthreads();
  }
  #pragma unroll
  for (int nt = 0; nt < 4; ++nt) {
    int g = nt0 * 128 + wn * 64 + nt * 16 + (lane & 15);
    float bv = bias[d * 2048 + g];
    int q = g >> 9, hbb = (g >> 4) & 31, u = g & 15;
    size_t base = ((((size_t)d * 32 + hbb) * TCH + tt) * 4 + q) * 2048 + u;
    #pragma unroll
    for (int mt = 0; mt < 4; ++mt)
      #pragma unroll
      for (int r = 0; r < 4; ++r) {
        int b = wm * 64 + mt * 16 + (lane >> 4) * 4 + r;
        gx[base + (size_t)b * 16] = f2bf(acc[mt][nt][r] + bv);
      }
  }
}

// ---- flag wait: wave0 lanes 0..31 poll 32 producer flags (64B-strided) ----
__device__ __forceinline__ void waitflags(const u32* fl, int lane, u32 target) {
  u32 v;
  do {
    v = (lane < 32)
      ? __hip_atomic_load(&fl[lane * 16], __ATOMIC_RELAXED, __HIP_MEMORY_SCOPE_AGENT)
      : target;
  } while (!__all((int)(v >= target)));
}

// 64 persistent blocks (1/CU). Block = (d, hb): owns h cols [hb*16, hb*16+16).
__global__ __launch_bounds__(256, 1) void k_scan(
    const float* __restrict__ Whf, const u16* __restrict__ gx,
    u16* __restrict__ hbuf,     // [pp=2][d=2][128][512] bf16, parity = global t
    u16* __restrict__ xout,     // [32768][1024] bf16 (concat dirs)
    float* __restrict__ cbuf,   // [2][128][512] f32
    u32* flags, u32 base, int t0)
{
  int tid = threadIdx.x, lane = tid & 63, w = tid >> 6;
  int d = blockIdx.x >> 5, hb = blockIdx.x & 31;
  const u32* fl = flags + d * 512;              // this direction's 32 flags
  u32* myflag = flags + (d * 32 + hb) * 16;
  __shared__ u16 WhL[64 * 512];
  for (int i = tid; i < 64 * 512; i += 256) {
    int r = i >> 9, k = i & 511;
    int grow = (r >> 4) * 512 + hb * 16 + (r & 15);       // gate row q*512 + hb*16 + u
    WhL[(r << 9) + (k ^ ((r & 7) << 3))] = f2bf(Whf[((size_t)d * 2048 + grow) * 512 + k]);
  }

  int bb = w * 32;                 // wave owns batch rows [bb, bb+32)
  int l15 = lane & 15, l4 = lane >> 4;
  int init1 = (t0 == 0) ? 1 : 0;
  float c[2][4];
  if (t0 == 0) {
    #pragma unroll
    for (int mt = 0; mt < 2; ++mt)
      #pragma unroll
      for (int r = 0; r < 4; ++r) c[mt][r] = 0.f;
    for (int i = tid; i < 512; i += 256) {      // zero own h_{-1} cols (pp=0), coherent
      int b = i >> 2, j = i & 3;
      u64* p = (u64*)(hbuf + ((size_t)d * 128 + b) * 512 + hb * 16) + j;
      __hip_atomic_store(p, 0ull, __ATOMIC_RELAXED, __HIP_MEMORY_SCOPE_AGENT);
    }
    __syncthreads();                            // drains zero-stores (vmcnt 0)
    if (tid == 0)
      __hip_atomic_store(myflag, base + 1, __ATOMIC_RELAXED, __HIP_MEMORY_SCOPE_AGENT);
  } else {
    #pragma unroll
    for (int mt = 0; mt < 2; ++mt)
      #pragma unroll
      for (int r = 0; r < 4; ++r) {
        int b = bb + mt * 16 + l4 * 4 + r;
        c[mt][r] = cbuf[((size_t)d * 128 + b) * 512 + hb * 16 + l15];
      }
  }

  // prefetch gates_x for step 0 (independent of flags)
  u16 gxv[2][4][4], gxn[2][4][4];
  {
    const u16* gxt = gx + (((size_t)d * 32 + hb) * TCH + 0) * 8192;
    #pragma unroll
    for (int mt = 0; mt < 2; ++mt)
      #pragma unroll
      for (int q = 0; q < 4; ++q)
        #pragma unroll
        for (int r = 0; r < 4; ++r)
          gxv[mt][q][r] = gxt[(q * 128 + bb + mt * 16 + l4 * 4 + r) * 16 + l15];
  }

  for (int tt = 0; tt < TCH; ++tt) {
    int t = t0 + tt;
    u32 target = base + (u32)tt + (u32)init1;
    if (w == 0 && !(tt == 0 && !init1)) waitflags(fl, lane, target);
    __syncthreads();                 // releases all waves; also covers WhL staging

    // h(t-1) coherent loads: issue all 32, single counted wait before MFMA use
    const u16* hp = hbuf + ((size_t)(t & 1) * 2 + d) * 128 * 512;
    const u16* hpA = hp + (size_t)(bb + l15) * 512 + l4 * 8;
    const u16* hpB = hp + (size_t)(bb + 16 + l15) * 512 + l4 * 8;
    bf16x8 a0s[16], a1s[16];
    #pragma unroll
    for (int kk = 0; kk < 16; ++kk) {
      a0s[kk] = ldh16(hpA + kk * 32);
      a1s[kk] = ldh16(hpB + kk * 32);
    }
    // prefetch next step's gates_x (independent; hides under h-load + MFMA)
    if (tt + 1 < TCH) {
      const u16* gxt = gx + (((size_t)d * 32 + hb) * TCH + (tt + 1)) * 8192;
      #pragma unroll
      for (int mt = 0; mt < 2; ++mt)
        #pragma unroll
        for (int q = 0; q < 4; ++q)
          #pragma unroll
          for (int r = 0; r < 4; ++r)
            gxn[mt][q][r] = gxt[(q * 128 + bb + mt * 16 + l4 * 4 + r) * 16 + l15];
    }

    f32x4 acc[2][4];
    #pragma unroll
    for (int mt = 0; mt < 2; ++mt)
      #pragma unroll
      for (int q = 0; q < 4; ++q) acc[mt][q] = f32x4{0.f, 0.f, 0.f, 0.f};
    #pragma unroll
    for (int kk = 0; kk < 16; ++kk) {
      int kbase = kk * 32 + l4 * 8;
      #pragma unroll
      for (int q = 0; q < 4; ++q) {
        int r = q * 16 + l15;
        bf16x8 bv = *(const bf16x8*)(&WhL[(r << 9) + (kbase ^ ((r & 7) << 3))]);
        acc[0][q] = __builtin_amdgcn_mfma_f32_16x16x32_bf16(a0s[kk], bv, acc[0][q], 0, 0, 0);
        acc[1][q] = __builtin_amdgcn_mfma_f32_16x16x32_bf16(a1s[kk], bv, acc[1][q], 0, 0, 0);
      }
    }
    u16* ho = hbuf + ((size_t)((t + 1) & 1) * 2 + d) * 128 * 512;
    #pragma unroll
    for (int mt = 0; mt < 2; ++mt)
      #pragma unroll
      for (int r = 0; r < 4; ++r) {
        int b = bb + mt * 16 + l4 * 4 + r;
        float gi = acc[mt][0][r] + bf2f(gxv[mt][0][r]);
        float gf = acc[mt][1][r] + bf2f(gxv[mt][1][r]);
        float gg = acc[mt][2][r] + bf2f(gxv[mt][2][r]);
        float go = acc[mt][3][r] + bf2f(gxv[mt][3][r]);
        float cn = sigm(gf) * c[mt][r] + sigm(gi) * tanh_(gg);
        float hn = sigm(go) * tanh_(cn);
        c[mt][r] = cn;
        u16 hv = f2bf(hn);
        sth(ho + (size_t)b * 512 + hb * 16 + l15, hv);                      // coherent
        xout[((size_t)t * 128 + b) * 1024 + d * 512 + hb * 16 + l15] = hv;  // cached
      }
    __syncthreads();                 // drains all waves' h-stores (vmcnt 0 at s_barrier)
    if (tid == 0)
      __hip_atomic_store(myflag, target + 1, __ATOMIC_RELAXED, __HIP_MEMORY_SCOPE_AGENT);
    // rotate gx prefetch
    #pragma unroll
    for (int mt = 0; mt < 2; ++mt)
      #pragma unroll
      for (int q = 0; q < 4; ++q)
        #pragma unroll
        for (int r = 0; r < 4; ++r)
          gxv[mt][q][r] = gxn[mt][q][r];
  }
  #pragma unroll
  for (int mt = 0; mt < 2; ++mt)
    #pragma unroll
    for (int r = 0; r < 4; ++r) {
      int b = bb + mt * 16 + l4 * 4 + r;
      cbuf[((size_t)d * 128 + b) * 512 + hb * 16 + l15] = c[mt][r];
    }
}

// ---------------- final: max over directions ----------------
__global__ void k_final(const u16* __restrict__ xin, float* __restrict__ out, int n) {
  int i = blockIdx.x * 256 + threadIdx.x;
  if (i >= n) return;
  int nrow = i >> 9, j = i & 511;
  float a = bf2f(xin[(size_t)nrow * 1024 + j]);
  float b = bf2f(xin[(size_t)nrow * 1024 + 512 + j]);
  out[i] = fmaxf(a, b);
}

extern "C" void kernel_launch(void* const* d_in, const int* in_sizes, int n_in,
                              void* d_out, int out_size, void* d_ws, size_t ws_size,
                              hipStream_t stream) {
  (void)in_sizes; (void)n_in; (void)out_size; (void)ws_size;
  const int*   tokens = (const int*)d_in[0];
  const float* embedW = (const float*)d_in[1];
  const float* W_ih0  = (const float*)d_in[2];
  const float* W_hh0  = (const float*)d_in[3];
  const float* b_ih0  = (const float*)d_in[4];
  const float* b_hh0  = (const float*)d_in[5];
  const float* W_ih   = (const float*)d_in[6];
  const float* W_hh   = (const float*)d_in[7];
  const float* b_ih   = (const float*)d_in[8];
  const float* b_hh   = (const float*)d_in[9];

  char* ws = (char*)d_ws;
  size_t off = 0;
  auto alloc = [&](size_t bytes) { void* p = ws + off; off += (bytes + 255) & ~(size_t)255; return p; };
  u16*   Wi_bf = (u16*)alloc(18087936ull * 2);   // [2][2048][320] + [4][2][2048][1024]
  float* biasC = (float*)alloc(20480ull * 4);    // [5][2][2048]
  u16*   Xbuf  = (u16*)alloc(33554432ull * 2);   // [32768][1024] single activation buffer
  u16*   gxbuf = (u16*)alloc(16777216ull * 2);   // [2][32][TCH][4][128][16] one chunk
  u16*   hbuf  = (u16*)alloc(262144ull * 2);     // [2][2][128][512]
  float* cbuf  = (float*)alloc(131072ull * 4);   // [2][128][512]
  u32*   flags = (u32*)alloc(8192);              // [2][32] flags, 64B-strided
  // total ~132 MB

  hipMemsetAsync(flags, 0, 8192, stream);

  k_cvt<<<1024, 256, 0, stream>>>(W_ih0, Wi_bf, 1310720);
  k_cvt<<<4096, 256, 0, stream>>>(W_ih,  Wi_bf + 1310720, 16777216);
  k_bias<<<80, 256, 0, stream>>>(b_ih0, b_hh0, b_ih, b_hh, biasC);

  u32 base = 0;
  for (int l = 0; l < 5; ++l) {
    int K = l ? 1024 : 320;
    const u16*   Wi_l  = l ? (Wi_bf + 1310720 + (size_t)(l - 1) * 4194304) : Wi_bf;
    const float* Whf_l = l ? (W_hh + (size_t)(l - 1) * 2097152) : W_hh0;
    const float* bias_l = biasC + (size_t)l * 4096;
    const float* embA = (l == 0) ? embedW : nullptr;
    const int*   tokA = (l == 0) ? tokens : nullptr;
    for (int ch = 0; ch < 256 / TCH; ++ch) {
      int t0 = ch * TCH;
      dim3 gg(32, TCH, 1);
      k_gemm<<<gg, 256, 0, stream>>>(Xbuf, embA, tokA, Wi_l, bias_l, gxbuf, K, t0);
      k_scan<<<64, 256, 0, stream>>>(Whf_l, gxbuf, hbuf, Xbuf, cbuf, flags, base, t0);
      base += 64;
    }
  }
  k_final<<<65536, 256, 0, stream>>>(Xbuf, (float*)d_out, 16777216);
}

// Round 5
// 13623.898 us; speedup vs baseline: 1.2568x; 1.2568x over previous
//
#include <hip/hip_runtime.h>
#include <stdint.h>

typedef unsigned short u16;
typedef unsigned int   u32;
typedef unsigned long long u64;
typedef short bf16x8 __attribute__((ext_vector_type(8)));
typedef float f32x4  __attribute__((ext_vector_type(4)));

static_assert(sizeof(bf16x8) == 16, "bf16x8 must be 16B");

#define LOG2E 1.4426950408889634f
#define TCH 32   // timesteps per chunk

__device__ __forceinline__ float bf2f(u16 u) { return __builtin_bit_cast(float, ((u32)u) << 16); }
__device__ __forceinline__ u16 f2bf(float f) {
  u32 x = __builtin_bit_cast(u32, f);
  return (u16)((x + 0x7fffu + ((x >> 16) & 1u)) >> 16);   // RNE, inputs are tame (no NaN)
}
__device__ __forceinline__ float sigm(float x) {
  return __builtin_amdgcn_rcpf(1.f + __builtin_amdgcn_exp2f(-LOG2E * x));
}
__device__ __forceinline__ float tanh_(float x) {
  return 1.f - 2.f * __builtin_amdgcn_rcpf(1.f + __builtin_amdgcn_exp2f(2.f * LOG2E * x));
}
__device__ __forceinline__ bf16x8 cvt8(const float* p) {
  bf16x8 r;
  #pragma unroll
  for (int j = 0; j < 8; ++j) r[j] = (short)f2bf(p[j]);
  return r;
}

// ---------------- prep kernels ----------------
__global__ void k_cvt(const float* __restrict__ src, u16* __restrict__ dst, int n) {
  int i = blockIdx.x * blockDim.x + threadIdx.x;
  int st = gridDim.x * blockDim.x;
  for (; i < n; i += st) dst[i] = f2bf(src[i]);
}

__global__ void k_bias(const float* __restrict__ bi0, const float* __restrict__ bh0,
                       const float* __restrict__ bi, const float* __restrict__ bh,
                       float* __restrict__ out) {
  int i = blockIdx.x * blockDim.x + threadIdx.x;
  if (i < 4096) out[i] = bi0[i] + bh0[i];
  else if (i < 20480) out[i] = bi[i - 4096] + bh[i - 4096];
}

// ---------------- input GEMM over one time-chunk ----------------
// gx layout (per d,hb,tt): [tid 0..255][mt 0..1][q 0..3][r 0..3] u16 — 64B/lane contiguous
__global__ __launch_bounds__(256) void k_gemm(
    const u16* __restrict__ X, const float* __restrict__ emb, const int* __restrict__ tok,
    const u16* __restrict__ Wi, const float* __restrict__ bias,
    u16* __restrict__ gx, int K, int t0)
{
  int d   = blockIdx.x >> 4;     // direction
  int nt0 = blockIdx.x & 15;     // N tile (128 gates)
  int tt  = blockIdx.y;          // timestep within chunk
  int t   = t0 + tt;
  __shared__ u16 As[128 * 64];
  __shared__ u16 Bs[128 * 64];
  __shared__ int s_tok[128];
  int tid = threadIdx.x, lane = tid & 63, w = tid >> 6;
  int wm = w & 1, wn = w >> 1;
  if (tok && tid < 128) s_tok[tid] = tok[t * 128 + tid];
  __syncthreads();

  const u16* Bbase = Wi + ((size_t)d * 2048 + nt0 * 128) * K;
  f32x4 acc[4][4];
  #pragma unroll
  for (int a = 0; a < 4; ++a)
    #pragma unroll
    for (int b = 0; b < 4; ++b) acc[a][b] = f32x4{0.f, 0.f, 0.f, 0.f};

  int nkt = K >> 6;  // K-tiles of 64
  for (int kt = 0; kt < nkt; ++kt) {
    #pragma unroll
    for (int i = 0; i < 4; ++i) {
      int s = tid + i * 256;              // slot 0..1023
      int row = s >> 3, c = s & 7;
      int cs = c ^ (row & 7);             // XOR-swizzle kills ds_read bank conflicts
      bf16x8 va;
      if (tok) {
        va = cvt8(emb + (size_t)s_tok[row] * 320 + kt * 64 + c * 8);
      } else {
        va = *(const bf16x8*)(X + ((size_t)t * 128 + row) * K + kt * 64 + c * 8);
      }
      bf16x8 vb = *(const bf16x8*)(Bbase + (size_t)row * K + kt * 64 + c * 8);
      *(bf16x8*)(&As[(row * 8 + cs) * 8]) = va;
      *(bf16x8*)(&Bs[(row * 8 + cs) * 8]) = vb;
    }
    __syncthreads();
    #pragma unroll
    for (int kk2 = 0; kk2 < 2; ++kk2) {
      int cl = kk2 * 4 + (lane >> 4);
      bf16x8 af[4], bfr[4];
      #pragma unroll
      for (int mt = 0; mt < 4; ++mt) {
        int row = wm * 64 + mt * 16 + (lane & 15);
        af[mt] = *(const bf16x8*)(&As[(row * 8 + (cl ^ (row & 7))) * 8]);
      }
      #pragma unroll
      for (int nt = 0; nt < 4; ++nt) {
        int row = wn * 64 + nt * 16 + (lane & 15);
        bfr[nt] = *(const bf16x8*)(&Bs[(row * 8 + (cl ^ (row & 7))) * 8]);
      }
      #pragma unroll
      for (int mt = 0; mt < 4; ++mt)
        #pragma unroll
        for (int nt = 0; nt < 4; ++nt)
          acc[mt][nt] = __builtin_amdgcn_mfma_f32_16x16x32_bf16(af[mt], bfr[nt], acc[mt][nt], 0, 0, 0);
    }
    __syncthreads();
  }
  #pragma unroll
  for (int nt = 0; nt < 4; ++nt) {
    int g = nt0 * 128 + wn * 64 + nt * 16 + (lane & 15);
    float bv = bias[d * 2048 + g];
    int q = g >> 9, hbb = (g >> 4) & 31, u = g & 15;
    size_t cb = (((size_t)d * 32 + hbb) * TCH + tt) * 8192;
    #pragma unroll
    for (int mt = 0; mt < 4; ++mt)
      #pragma unroll
      for (int r = 0; r < 4; ++r) {
        int b = wm * 64 + mt * 16 + (lane >> 4) * 4 + r;
        int ws = b >> 5, mts = (b >> 4) & 1, l4s = (b >> 2) & 3, rs = b & 3;
        gx[cb + (size_t)(ws * 64 + l4s * 16 + u) * 32 + mts * 16 + q * 4 + rs]
          = f2bf(acc[mt][nt][r] + bv);
      }
  }
}

// ---- flag wait: wave0 lanes 0..31 poll 32 producer flags (64B-strided) ----
__device__ __forceinline__ void waitflags(const u32* fl, int lane, u32 target) {
  u32 v;
  do {
    v = (lane < 32)
      ? __hip_atomic_load(&fl[lane * 16], __ATOMIC_RELAXED, __HIP_MEMORY_SCOPE_AGENT)
      : target;
  } while (!__all((int)(v >= target)));
}

// 64 persistent blocks (1/CU). Block = (d, hb): owns h cols [hb*16, hb*16+16).
__global__ __launch_bounds__(256, 1) void k_scan(
    const float* __restrict__ Whf, const u16* __restrict__ gx,
    u16* __restrict__ hbuf,     // [pp=2][d=2][128][512] bf16, parity = global t
    u16* __restrict__ xout,     // [32768][1024] bf16 (concat dirs)
    float* __restrict__ cbuf,   // [2][128][512] f32
    u32* flags, u32 base, int t0)
{
  int tid = threadIdx.x, lane = tid & 63, w = tid >> 6;
  int d = blockIdx.x >> 5, hb = blockIdx.x & 31;
  const u32* fl = flags + d * 512;              // this direction's 32 flags
  u32* myflag = flags + (d * 32 + hb) * 16;
  __shared__ u16 WhL[64 * 512];
  for (int i = tid; i < 64 * 512; i += 256) {
    int r = i >> 9, k = i & 511;
    int grow = (r >> 4) * 512 + hb * 16 + (r & 15);       // gate row q*512 + hb*16 + u
    WhL[(r << 9) + (k ^ ((r & 7) << 3))] = f2bf(Whf[((size_t)d * 2048 + grow) * 512 + k]);
  }

  int bb = w * 32;                 // wave owns batch rows [bb, bb+32)
  int l15 = lane & 15, l4 = lane >> 4;
  int init1 = (t0 == 0) ? 1 : 0;
  float c[2][4];
  if (t0 == 0) {
    #pragma unroll
    for (int mt = 0; mt < 2; ++mt)
      #pragma unroll
      for (int r = 0; r < 4; ++r) c[mt][r] = 0.f;
    for (int i = tid; i < 512; i += 256) {      // zero own h_{-1} cols (pp=0), coherent
      int b = i >> 2, j = i & 3;
      u64* p = (u64*)(hbuf + ((size_t)d * 128 + b) * 512 + hb * 16) + j;
      __hip_atomic_store(p, 0ull, __ATOMIC_RELAXED, __HIP_MEMORY_SCOPE_AGENT);
    }
    __syncthreads();                            // drains zero-stores
    if (tid == 0)
      __hip_atomic_store(myflag, base + 1, __ATOMIC_RELAXED, __HIP_MEMORY_SCOPE_AGENT);
  } else {
    #pragma unroll
    for (int mt = 0; mt < 2; ++mt)
      #pragma unroll
      for (int r = 0; r < 4; ++r) {
        int b = bb + mt * 16 + l4 * 4 + r;
        c[mt][r] = cbuf[((size_t)d * 128 + b) * 512 + hb * 16 + l15];
      }
  }

  const u16* gxblk = gx + ((size_t)d * 32 + hb) * TCH * 8192 + (size_t)tid * 32;
  // prefetch gates_x for step 0 (4x16B contiguous per lane)
  bf16x8 gxv4[4], gxn4[4];
  #pragma unroll
  for (int j = 0; j < 4; ++j) gxv4[j] = *(const bf16x8*)(gxblk + j * 8);

  for (int tt = 0; tt < TCH; ++tt) {
    int t = t0 + tt;
    u32 target = base + (u32)tt + (u32)init1;
    if (w == 0 && !(tt == 0 && !init1)) waitflags(fl, lane, target);
    __syncthreads();                 // releases all waves; also covers WhL staging

    // h(t-1): 32x16B coherent loads, single asm burst, one vmcnt(0) at the end
    const u16* hp = hbuf + ((size_t)(t & 1) * 2 + d) * 128 * 512;
    const u16* hpA = hp + (size_t)(bb + l15) * 512 + l4 * 8;
    const u16* hpB = hp + (size_t)(bb + 16 + l15) * 512 + l4 * 8;
    f32x4 h0[16], h1[16];
    asm volatile(
      "global_load_dwordx4 %0, %8, off sc0 sc1\n\t"
      "global_load_dwordx4 %1, %8, off offset:64 sc0 sc1\n\t"
      "global_load_dwordx4 %2, %8, off offset:128 sc0 sc1\n\t"
      "global_load_dwordx4 %3, %8, off offset:192 sc0 sc1\n\t"
      "global_load_dwordx4 %4, %8, off offset:256 sc0 sc1\n\t"
      "global_load_dwordx4 %5, %8, off offset:320 sc0 sc1\n\t"
      "global_load_dwordx4 %6, %8, off offset:384 sc0 sc1\n\t"
      "global_load_dwordx4 %7, %8, off offset:448 sc0 sc1"
      : "=v"(h0[0]), "=v"(h0[1]), "=v"(h0[2]), "=v"(h0[3]),
        "=v"(h0[4]), "=v"(h0[5]), "=v"(h0[6]), "=v"(h0[7])
      : "v"(hpA) : "memory");
    asm volatile(
      "global_load_dwordx4 %0, %8, off offset:512 sc0 sc1\n\t"
      "global_load_dwordx4 %1, %8, off offset:576 sc0 sc1\n\t"
      "global_load_dwordx4 %2, %8, off offset:640 sc0 sc1\n\t"
      "global_load_dwordx4 %3, %8, off offset:704 sc0 sc1\n\t"
      "global_load_dwordx4 %4, %8, off offset:768 sc0 sc1\n\t"
      "global_load_dwordx4 %5, %8, off offset:832 sc0 sc1\n\t"
      "global_load_dwordx4 %6, %8, off offset:896 sc0 sc1\n\t"
      "global_load_dwordx4 %7, %8, off offset:960 sc0 sc1"
      : "=v"(h0[8]), "=v"(h0[9]), "=v"(h0[10]), "=v"(h0[11]),
        "=v"(h0[12]), "=v"(h0[13]), "=v"(h0[14]), "=v"(h0[15])
      : "v"(hpA) : "memory");
    asm volatile(
      "global_load_dwordx4 %0, %8, off sc0 sc1\n\t"
      "global_load_dwordx4 %1, %8, off offset:64 sc0 sc1\n\t"
      "global_load_dwordx4 %2, %8, off offset:128 sc0 sc1\n\t"
      "global_load_dwordx4 %3, %8, off offset:192 sc0 sc1\n\t"
      "global_load_dwordx4 %4, %8, off offset:256 sc0 sc1\n\t"
      "global_load_dwordx4 %5, %8, off offset:320 sc0 sc1\n\t"
      "global_load_dwordx4 %6, %8, off offset:384 sc0 sc1\n\t"
      "global_load_dwordx4 %7, %8, off offset:448 sc0 sc1"
      : "=v"(h1[0]), "=v"(h1[1]), "=v"(h1[2]), "=v"(h1[3]),
        "=v"(h1[4]), "=v"(h1[5]), "=v"(h1[6]), "=v"(h1[7])
      : "v"(hpB) : "memory");
    asm volatile(
      "global_load_dwordx4 %0, %8, off offset:512 sc0 sc1\n\t"
      "global_load_dwordx4 %1, %8, off offset:576 sc0 sc1\n\t"
      "global_load_dwordx4 %2, %8, off offset:640 sc0 sc1\n\t"
      "global_load_dwordx4 %3, %8, off offset:704 sc0 sc1\n\t"
      "global_load_dwordx4 %4, %8, off offset:768 sc0 sc1\n\t"
      "global_load_dwordx4 %5, %8, off offset:832 sc0 sc1\n\t"
      "global_load_dwordx4 %6, %8, off offset:896 sc0 sc1\n\t"
      "global_load_dwordx4 %7, %8, off offset:960 sc0 sc1\n\t"
      "s_waitcnt vmcnt(0)"
      : "=v"(h1[8]), "=v"(h1[9]), "=v"(h1[10]), "=v"(h1[11]),
        "=v"(h1[12]), "=v"(h1[13]), "=v"(h1[14]), "=v"(h1[15])
      : "v"(hpB) : "memory");
    __builtin_amdgcn_sched_barrier(0);

    // prefetch next step's gates_x (overlaps MFMA)
    if (tt + 1 < TCH) {
      const u16* gp = gxblk + (size_t)(tt + 1) * 8192;
      #pragma unroll
      for (int j = 0; j < 4; ++j) gxn4[j] = *(const bf16x8*)(gp + j * 8);
    }

    f32x4 acc[2][4];
    #pragma unroll
    for (int mt = 0; mt < 2; ++mt)
      #pragma unroll
      for (int q = 0; q < 4; ++q) acc[mt][q] = f32x4{0.f, 0.f, 0.f, 0.f};
    #pragma unroll
    for (int kk = 0; kk < 16; ++kk) {
      int kbase = kk * 32 + l4 * 8;
      bf16x8 a0 = __builtin_bit_cast(bf16x8, h0[kk]);
      bf16x8 a1 = __builtin_bit_cast(bf16x8, h1[kk]);
      #pragma unroll
      for (int q = 0; q < 4; ++q) {
        int r = q * 16 + l15;
        bf16x8 bv = *(const bf16x8*)(&WhL[(r << 9) + (kbase ^ ((r & 7) << 3))]);
        acc[0][q] = __builtin_amdgcn_mfma_f32_16x16x32_bf16(a0, bv, acc[0][q], 0, 0, 0);
        acc[1][q] = __builtin_amdgcn_mfma_f32_16x16x32_bf16(a1, bv, acc[1][q], 0, 0, 0);
      }
    }
    u16* ho = hbuf + ((size_t)((t + 1) & 1) * 2 + d) * 128 * 512;
    u32 hvv[2][4];
    float hnf[2][4];
    #pragma unroll
    for (int mt = 0; mt < 2; ++mt)
      #pragma unroll
      for (int r = 0; r < 4; ++r) {
        // gx vecs: value(mt,q,r) = gxv4[mt*2 + (q>>1)][(q&1)*4 + r]
        float gi = acc[mt][0][r] + bf2f((u16)gxv4[mt * 2][r]);
        float gf = acc[mt][1][r] + bf2f((u16)gxv4[mt * 2][4 + r]);
        float gg = acc[mt][2][r] + bf2f((u16)gxv4[mt * 2 + 1][r]);
        float go = acc[mt][3][r] + bf2f((u16)gxv4[mt * 2 + 1][4 + r]);
        float cn = sigm(gf) * c[mt][r] + sigm(gi) * tanh_(gg);
        float hn = sigm(go) * tanh_(cn);
        c[mt][r] = cn;
        hnf[mt][r] = hn;
        hvv[mt][r] = (u32)f2bf(hn);
      }
    // coherent h-stores: 8x 2B write-through, then drain before flag
    {
      u16* st0 = ho + (size_t)(bb + l4 * 4) * 512 + hb * 16 + l15;
      u16* st1 = st0 + 16 * 512;
      asm volatile(
        "global_store_short %8, %0, off sc0 sc1\n\t"
        "global_store_short %8, %1, off offset:1024 sc0 sc1\n\t"
        "global_store_short %8, %2, off offset:2048 sc0 sc1\n\t"
        "global_store_short %8, %3, off offset:3072 sc0 sc1\n\t"
        "global_store_short %9, %4, off sc0 sc1\n\t"
        "global_store_short %9, %5, off offset:1024 sc0 sc1\n\t"
        "global_store_short %9, %6, off offset:2048 sc0 sc1\n\t"
        "global_store_short %9, %7, off offset:3072 sc0 sc1\n\t"
        "s_waitcnt vmcnt(0)"
        :: "v"(hvv[0][0]), "v"(hvv[0][1]), "v"(hvv[0][2]), "v"(hvv[0][3]),
           "v"(hvv[1][0]), "v"(hvv[1][1]), "v"(hvv[1][2]), "v"(hvv[1][3]),
           "v"(st0), "v"(st1)
        : "memory");
    }
    __syncthreads();
    if (tid == 0)
      __hip_atomic_store(myflag, target + 1, __ATOMIC_RELAXED, __HIP_MEMORY_SCOPE_AGENT);
    // xout stores off the critical path (plain cached)
    #pragma unroll
    for (int mt = 0; mt < 2; ++mt)
      #pragma unroll
      for (int r = 0; r < 4; ++r) {
        int b = bb + mt * 16 + l4 * 4 + r;
        xout[((size_t)t * 128 + b) * 1024 + d * 512 + hb * 16 + l15] = f2bf(hnf[mt][r]);
      }
    #pragma unroll
    for (int j = 0; j < 4; ++j) gxv4[j] = gxn4[j];
  }
  #pragma unroll
  for (int mt = 0; mt < 2; ++mt)
    #pragma unroll
    for (int r = 0; r < 4; ++r) {
      int b = bb + mt * 16 + l4 * 4 + r;
      cbuf[((size_t)d * 128 + b) * 512 + hb * 16 + l15] = c[mt][r];
    }
}

// ---------------- final: max over directions ----------------
__global__ void k_final(const u16* __restrict__ xin, float* __restrict__ out, int n) {
  int i = blockIdx.x * 256 + threadIdx.x;
  if (i >= n) return;
  int nrow = i >> 9, j = i & 511;
  float a = bf2f(xin[(size_t)nrow * 1024 + j]);
  float b = bf2f(xin[(size_t)nrow * 1024 + 512 + j]);
  out[i] = fmaxf(a, b);
}

extern "C" void kernel_launch(void* const* d_in, const int* in_sizes, int n_in,
                              void* d_out, int out_size, void* d_ws, size_t ws_size,
                              hipStream_t stream) {
  (void)in_sizes; (void)n_in; (void)out_size; (void)ws_size;
  const int*   tokens = (const int*)d_in[0];
  const float* embedW = (const float*)d_in[1];
  const float* W_ih0  = (const float*)d_in[2];
  const float* W_hh0  = (const float*)d_in[3];
  const float* b_ih0  = (const float*)d_in[4];
  const float* b_hh0  = (const float*)d_in[5];
  const float* W_ih   = (const float*)d_in[6];
  const float* W_hh   = (const float*)d_in[7];
  const float* b_ih   = (const float*)d_in[8];
  const float* b_hh   = (const float*)d_in[9];

  char* ws = (char*)d_ws;
  size_t off = 0;
  auto alloc = [&](size_t bytes) { void* p = ws + off; off += (bytes + 255) & ~(size_t)255; return p; };
  u16*   Wi_bf = (u16*)alloc(18087936ull * 2);   // [2][2048][320] + [4][2][2048][1024]
  float* biasC = (float*)alloc(20480ull * 4);    // [5][2][2048]
  u16*   Xbuf  = (u16*)alloc(33554432ull * 2);   // [32768][1024] single activation buffer
  u16*   gxbuf = (u16*)alloc(16777216ull * 2);   // [2][32][TCH][256][32] one chunk
  u16*   hbuf  = (u16*)alloc(262144ull * 2);     // [2][2][128][512]
  float* cbuf  = (float*)alloc(131072ull * 4);   // [2][128][512]
  u32*   flags = (u32*)alloc(8192);              // [2][32] flags, 64B-strided
  // total ~132 MB

  hipMemsetAsync(flags, 0, 8192, stream);

  k_cvt<<<1024, 256, 0, stream>>>(W_ih0, Wi_bf, 1310720);
  k_cvt<<<4096, 256, 0, stream>>>(W_ih,  Wi_bf + 1310720, 16777216);
  k_bias<<<80, 256, 0, stream>>>(b_ih0, b_hh0, b_ih, b_hh, biasC);

  u32 base = 0;
  for (int l = 0; l < 5; ++l) {
    int K = l ? 1024 : 320;
    const u16*   Wi_l  = l ? (Wi_bf + 1310720 + (size_t)(l - 1) * 4194304) : Wi_bf;
    const float* Whf_l = l ? (W_hh + (size_t)(l - 1) * 2097152) : W_hh0;
    const float* bias_l = biasC + (size_t)l * 4096;
    const float* embA = (l == 0) ? embedW : nullptr;
    const int*   tokA = (l == 0) ? tokens : nullptr;
    for (int ch = 0; ch < 256 / TCH; ++ch) {
      int t0 = ch * TCH;
      dim3 gg(32, TCH, 1);
      k_gemm<<<gg, 256, 0, stream>>>(Xbuf, embA, tokA, Wi_l, bias_l, gxbuf, K, t0);
      k_scan<<<64, 256, 0, stream>>>(Whf_l, gxbuf, hbuf, Xbuf, cbuf, flags, base, t0);
      base += 64;
    }
  }
  k_final<<<65536, 256, 0, stream>>>(Xbuf, (float*)d_out, 16777216);
}

// Round 6
// 11036.506 us; speedup vs baseline: 1.5515x; 1.2344x over previous
//
#include <hip/hip_runtime.h>
#include <stdint.h>

typedef unsigned short u16;
typedef unsigned int   u32;
typedef unsigned long long u64;
typedef short bf16x8 __attribute__((ext_vector_type(8)));
typedef float f32x4  __attribute__((ext_vector_type(4)));

static_assert(sizeof(bf16x8) == 16, "bf16x8 must be 16B");

#define LOG2E 1.4426950408889634f
#define TCH 32
#define NSLOT 131072   // u16 elems per hbuf time slot: 2 dirs * 128 * 512
#define HDIR  65536    // u16 elems per direction within a slot

__device__ __forceinline__ float bf2f(u16 u) { return __builtin_bit_cast(float, ((u32)u) << 16); }
__device__ __forceinline__ u16 f2bf(float f) {
  u32 x = __builtin_bit_cast(u32, f);
  return (u16)((x + 0x7fffu + ((x >> 16) & 1u)) >> 16);
}
__device__ __forceinline__ float sigm(float x) {
  return __builtin_amdgcn_rcpf(1.f + __builtin_amdgcn_exp2f(-LOG2E * x));
}
__device__ __forceinline__ float tanh_(float x) {
  return 1.f - 2.f * __builtin_amdgcn_rcpf(1.f + __builtin_amdgcn_exp2f(2.f * LOG2E * x));
}
__device__ __forceinline__ bf16x8 cvt8(const float* p) {
  bf16x8 r;
  #pragma unroll
  for (int j = 0; j < 8; ++j) r[j] = (short)f2bf(p[j]);
  return r;
}

// ---------------- prep ----------------
__global__ void k_bias(const float* __restrict__ bi0, const float* __restrict__ bh0,
                       const float* __restrict__ bi, const float* __restrict__ bh,
                       float* __restrict__ out) {
  int i = blockIdx.x * blockDim.x + threadIdx.x;
  if (i < 4096) out[i] = bi0[i] + bh0[i];
  else if (i < 20480) out[i] = bi[i - 4096] + bh[i - 4096];
}

// ---------------- GEMM tile (device): one 128x128 tile for (d, nt0, tt) ----------------
// A: tok!=null -> embed[tokens] gather (K=320, fp32); else hbuf slots (bf16, layer l-1 h).
// B: Wi fp32, converted on the fly. Output gx in scan lane-major layout.
__device__ __forceinline__ void gemm_tile(
    u16* smem, const u16* hb, const float* emb, const int* tok,
    const float* Wif, const float* bias, u16* gx, int K, int t0,
    int d, int nt0, int tt)
{
  u16* As = smem;
  u16* Bs = smem + 8192;
  int* s_tok = (int*)(smem + 16384);
  int tid = threadIdx.x, lane = tid & 63, w = tid >> 6;
  int wm = w & 1, wn = w >> 1;
  int t = t0 + tt;
  if (tok && tid < 128) s_tok[tid] = tok[t * 128 + tid];
  __syncthreads();

  const float* Bbase = Wif + ((size_t)d * 2048 + nt0 * 128) * K;
  f32x4 acc[4][4];
  #pragma unroll
  for (int a = 0; a < 4; ++a)
    #pragma unroll
    for (int b = 0; b < 4; ++b) acc[a][b] = f32x4{0.f, 0.f, 0.f, 0.f};

  int nkt = K >> 6;
  for (int kt = 0; kt < nkt; ++kt) {
    #pragma unroll
    for (int i = 0; i < 4; ++i) {
      int s = tid + i * 256;
      int row = s >> 3, c = s & 7;
      int cs = c ^ (row & 7);
      bf16x8 va;
      if (tok) {
        va = cvt8(emb + (size_t)s_tok[row] * 320 + kt * 64 + c * 8);
      } else {
        int k = kt * 64 + c * 8;
        va = *(const bf16x8*)(hb + (size_t)(t + 1) * NSLOT + (size_t)(k >> 9) * HDIR
                              + (size_t)row * 512 + (k & 511));
      }
      bf16x8 vb = cvt8(Bbase + (size_t)row * K + kt * 64 + c * 8);
      *(bf16x8*)(&As[(row * 8 + cs) * 8]) = va;
      *(bf16x8*)(&Bs[(row * 8 + cs) * 8]) = vb;
    }
    __syncthreads();
    #pragma unroll
    for (int kk2 = 0; kk2 < 2; ++kk2) {
      int cl = kk2 * 4 + (lane >> 4);
      bf16x8 af[4], bfr[4];
      #pragma unroll
      for (int mt = 0; mt < 4; ++mt) {
        int row = wm * 64 + mt * 16 + (lane & 15);
        af[mt] = *(const bf16x8*)(&As[(row * 8 + (cl ^ (row & 7))) * 8]);
      }
      #pragma unroll
      for (int nt = 0; nt < 4; ++nt) {
        int row = wn * 64 + nt * 16 + (lane & 15);
        bfr[nt] = *(const bf16x8*)(&Bs[(row * 8 + (cl ^ (row & 7))) * 8]);
      }
      #pragma unroll
      for (int mt = 0; mt < 4; ++mt)
        #pragma unroll
        for (int nt = 0; nt < 4; ++nt)
          acc[mt][nt] = __builtin_amdgcn_mfma_f32_16x16x32_bf16(af[mt], bfr[nt], acc[mt][nt], 0, 0, 0);
    }
    __syncthreads();
  }
  #pragma unroll
  for (int nt = 0; nt < 4; ++nt) {
    int g = nt0 * 128 + wn * 64 + nt * 16 + (lane & 15);
    float bv = bias[d * 2048 + g];
    int q = g >> 9, hbb = (g >> 4) & 31, u = g & 15;
    size_t cb = (((size_t)d * 32 + hbb) * TCH + tt) * 8192;
    #pragma unroll
    for (int mt = 0; mt < 4; ++mt)
      #pragma unroll
      for (int r = 0; r < 4; ++r) {
        int b = wm * 64 + mt * 16 + (lane >> 4) * 4 + r;
        int ws2 = b >> 5, mts = (b >> 4) & 1, l4s = (b >> 2) & 3, rs = b & 3;
        gx[cb + (size_t)(ws2 * 64 + l4s * 16 + u) * 32 + mts * 16 + q * 4 + rs]
          = f2bf(acc[mt][nt][r] + bv);
      }
  }
}

// ---------------- prologue GEMM: layer 0 chunk 0 ----------------
__global__ __launch_bounds__(256) void k_gemm0(
    const float* __restrict__ emb, const int* __restrict__ tok,
    const float* __restrict__ Wif, const float* __restrict__ bias, u16* __restrict__ gx)
{
  __shared__ __align__(16) u16 smem[16640];
  int xt = blockIdx.x;
  gemm_tile(smem, nullptr, emb, tok, Wif, bias, gx, 320, 0, xt >> 4, xt & 15, blockIdx.y);
}

// ---- flag wait: lanes 0..31 poll the 32 producer flags (64B-strided); all waves poll ----
__device__ __forceinline__ void waitflags(const u32* fl, int lane, u32 target) {
  u32 v;
  do {
    v = (lane < 32)
      ? __hip_atomic_load(&fl[lane * 16], __ATOMIC_RELAXED, __HIP_MEMORY_SCOPE_AGENT)
      : target;
  } while (!__all((int)(v >= target)));
}

// ---------------- fused kernel: blocks 0..63 scan chunk c; blocks 64..319 GEMM next chunk ----------------
__global__ __launch_bounds__(256, 2) void k_fused(
    const float* __restrict__ Whf, const u16* __restrict__ gx_s,
    u16* __restrict__ hb, float* __restrict__ cbuf,
    u32* flags, u32 base, int t0, int hz,
    const float* __restrict__ emb, const int* __restrict__ tok_g,
    const float* __restrict__ Wif_g, const float* __restrict__ bias_g,
    u16* __restrict__ gx_g, int Kg, int t0g)
{
  __shared__ __align__(16) u16 smem[32768];   // scan: WhL 64KB; gemm: As/Bs/s_tok
  int tid = threadIdx.x, lane = tid & 63, w = tid >> 6;

  if (blockIdx.x >= 64) {          // ---------- GEMM role ----------
    if (t0g < 0) return;
    #pragma unroll 1
    for (int i = 0; i < 4; ++i) {
      int tau = (blockIdx.x - 64) + i * 256;   // 0..1023
      int xt = tau & 31, tt = tau >> 5;
      gemm_tile(smem, hb, emb, tok_g, Wif_g, bias_g, gx_g, Kg, t0g, xt >> 4, xt & 15, tt);
      __syncthreads();
    }
    return;
  }

  // ---------- scan role ----------
  int d = blockIdx.x >> 5, hb_i = blockIdx.x & 31;
  const u32* fl = flags + d * 512;
  u32* myflag = flags + (d * 32 + hb_i) * 16;
  u16* WhL = smem;
  for (int i = tid; i < 64 * 512; i += 256) {
    int r = i >> 9, k = i & 511;
    int grow = (r >> 4) * 512 + hb_i * 16 + (r & 15);
    WhL[(r << 9) + (k ^ ((r & 7) << 3))] = f2bf(Whf[((size_t)d * 2048 + grow) * 512 + k]);
  }

  int bb = w * 32;
  int l15 = lane & 15, l4 = lane >> 4;
  float c2[2][4];
  if (t0 == 0) {
    #pragma unroll
    for (int mt = 0; mt < 2; ++mt)
      #pragma unroll
      for (int r = 0; r < 4; ++r) c2[mt][r] = 0.f;
  } else {
    #pragma unroll
    for (int mt = 0; mt < 2; ++mt)
      #pragma unroll
      for (int r = 0; r < 4; ++r) {
        int b = bb + mt * 16 + l4 * 4 + r;
        c2[mt][r] = cbuf[((size_t)d * 128 + b) * 512 + hb_i * 16 + l15];
      }
  }
  if (hz) {   // zero h(-1): slot 0, own columns (coherent stores)
    for (int i = tid; i < 512; i += 256) {
      int b = i >> 2, j = i & 3;
      u64* p = (u64*)(hb + (size_t)d * HDIR + (size_t)b * 512 + hb_i * 16) + j;
      __hip_atomic_store(p, 0ull, __ATOMIC_RELAXED, __HIP_MEMORY_SCOPE_AGENT);
    }
  }
  __syncthreads();   // WhL staged + zero-stores drained (sync implies vmcnt(0))
  if (hz && tid == 0)
    __hip_atomic_store(myflag, base + 1, __ATOMIC_RELAXED, __HIP_MEMORY_SCOPE_AGENT);
  int init1 = hz ? 1 : 0;

  const u16* gxblk = gx_s + ((size_t)d * 32 + hb_i) * TCH * 8192 + (size_t)tid * 32;
  bf16x8 gxv4[4], gxn4[4];
  #pragma unroll
  for (int j = 0; j < 4; ++j) gxv4[j] = *(const bf16x8*)(gxblk + j * 8);
  #pragma unroll
  for (int j = 0; j < 4; ++j) gxn4[j] = *(const bf16x8*)(gxblk + 8192 + j * 8);

  for (int tt = 0; tt < TCH; ++tt) {
    int t = t0 + tt;
    u32 target = base + (u32)tt + (u32)init1;
    if (!(tt == 0 && !init1)) waitflags(fl, lane, target);   // every wave polls

    // h(t-1): 32x16B coherent loads, single burst, one vmcnt(0)
    const u16* hp = hb + (size_t)t * NSLOT + (size_t)d * HDIR;
    const u16* hpA = hp + (size_t)(bb + l15) * 512 + l4 * 8;
    const u16* hpB = hp + (size_t)(bb + 16 + l15) * 512 + l4 * 8;
    f32x4 h0[16], h1[16];
    asm volatile(
      "global_load_dwordx4 %0, %8, off sc0 sc1\n\t"
      "global_load_dwordx4 %1, %8, off offset:64 sc0 sc1\n\t"
      "global_load_dwordx4 %2, %8, off offset:128 sc0 sc1\n\t"
      "global_load_dwordx4 %3, %8, off offset:192 sc0 sc1\n\t"
      "global_load_dwordx4 %4, %8, off offset:256 sc0 sc1\n\t"
      "global_load_dwordx4 %5, %8, off offset:320 sc0 sc1\n\t"
      "global_load_dwordx4 %6, %8, off offset:384 sc0 sc1\n\t"
      "global_load_dwordx4 %7, %8, off offset:448 sc0 sc1"
      : "=v"(h0[0]), "=v"(h0[1]), "=v"(h0[2]), "=v"(h0[3]),
        "=v"(h0[4]), "=v"(h0[5]), "=v"(h0[6]), "=v"(h0[7])
      : "v"(hpA) : "memory");
    asm volatile(
      "global_load_dwordx4 %0, %8, off offset:512 sc0 sc1\n\t"
      "global_load_dwordx4 %1, %8, off offset:576 sc0 sc1\n\t"
      "global_load_dwordx4 %2, %8, off offset:640 sc0 sc1\n\t"
      "global_load_dwordx4 %3, %8, off offset:704 sc0 sc1\n\t"
      "global_load_dwordx4 %4, %8, off offset:768 sc0 sc1\n\t"
      "global_load_dwordx4 %5, %8, off offset:832 sc0 sc1\n\t"
      "global_load_dwordx4 %6, %8, off offset:896 sc0 sc1\n\t"
      "global_load_dwordx4 %7, %8, off offset:960 sc0 sc1"
      : "=v"(h0[8]), "=v"(h0[9]), "=v"(h0[10]), "=v"(h0[11]),
        "=v"(h0[12]), "=v"(h0[13]), "=v"(h0[14]), "=v"(h0[15])
      : "v"(hpA) : "memory");
    asm volatile(
      "global_load_dwordx4 %0, %8, off sc0 sc1\n\t"
      "global_load_dwordx4 %1, %8, off offset:64 sc0 sc1\n\t"
      "global_load_dwordx4 %2, %8, off offset:128 sc0 sc1\n\t"
      "global_load_dwordx4 %3, %8, off offset:192 sc0 sc1\n\t"
      "global_load_dwordx4 %4, %8, off offset:256 sc0 sc1\n\t"
      "global_load_dwordx4 %5, %8, off offset:320 sc0 sc1\n\t"
      "global_load_dwordx4 %6, %8, off offset:384 sc0 sc1\n\t"
      "global_load_dwordx4 %7, %8, off offset:448 sc0 sc1"
      : "=v"(h1[0]), "=v"(h1[1]), "=v"(h1[2]), "=v"(h1[3]),
        "=v"(h1[4]), "=v"(h1[5]), "=v"(h1[6]), "=v"(h1[7])
      : "v"(hpB) : "memory");
    asm volatile(
      "global_load_dwordx4 %0, %8, off offset:512 sc0 sc1\n\t"
      "global_load_dwordx4 %1, %8, off offset:576 sc0 sc1\n\t"
      "global_load_dwordx4 %2, %8, off offset:640 sc0 sc1\n\t"
      "global_load_dwordx4 %3, %8, off offset:704 sc0 sc1\n\t"
      "global_load_dwordx4 %4, %8, off offset:768 sc0 sc1\n\t"
      "global_load_dwordx4 %5, %8, off offset:832 sc0 sc1\n\t"
      "global_load_dwordx4 %6, %8, off offset:896 sc0 sc1\n\t"
      "global_load_dwordx4 %7, %8, off offset:960 sc0 sc1\n\t"
      "s_waitcnt vmcnt(0)"
      : "=v"(h1[8]), "=v"(h1[9]), "=v"(h1[10]), "=v"(h1[11]),
        "=v"(h1[12]), "=v"(h1[13]), "=v"(h1[14]), "=v"(h1[15])
      : "v"(hpB) : "memory");
    __builtin_amdgcn_sched_barrier(0);

    f32x4 acc[2][4];
    #pragma unroll
    for (int mt = 0; mt < 2; ++mt)
      #pragma unroll
      for (int q = 0; q < 4; ++q) acc[mt][q] = f32x4{0.f, 0.f, 0.f, 0.f};
    #pragma unroll
    for (int kk = 0; kk < 16; ++kk) {
      int kbase = kk * 32 + l4 * 8;
      bf16x8 a0 = __builtin_bit_cast(bf16x8, h0[kk]);
      bf16x8 a1 = __builtin_bit_cast(bf16x8, h1[kk]);
      #pragma unroll
      for (int q = 0; q < 4; ++q) {
        int r = q * 16 + l15;
        bf16x8 bv = *(const bf16x8*)(&WhL[(r << 9) + (kbase ^ ((r & 7) << 3))]);
        acc[0][q] = __builtin_amdgcn_mfma_f32_16x16x32_bf16(a0, bv, acc[0][q], 0, 0, 0);
        acc[1][q] = __builtin_amdgcn_mfma_f32_16x16x32_bf16(a1, bv, acc[1][q], 0, 0, 0);
      }
    }
    u16* ho = hb + (size_t)(t + 1) * NSLOT + (size_t)d * HDIR;
    u32 hvv[2][4];
    #pragma unroll
    for (int mt = 0; mt < 2; ++mt)
      #pragma unroll
      for (int r = 0; r < 4; ++r) {
        float gi = acc[mt][0][r] + bf2f((u16)gxv4[mt * 2][r]);
        float gf = acc[mt][1][r] + bf2f((u16)gxv4[mt * 2][4 + r]);
        float gg = acc[mt][2][r] + bf2f((u16)gxv4[mt * 2 + 1][r]);
        float go = acc[mt][3][r] + bf2f((u16)gxv4[mt * 2 + 1][4 + r]);
        float cn = sigm(gf) * c2[mt][r] + sigm(gi) * tanh_(gg);
        float hn = sigm(go) * tanh_(cn);
        c2[mt][r] = cn;
        hvv[mt][r] = (u32)f2bf(hn);
      }
    // 8 coherent h-stores + 4 gx(t+2) prefetch loads in ONE asm block, counted wait:
    // at entry outstanding vmem == 0 (h-burst drained, poll loads consumed), so
    // vmcnt(4) == all 8 stores done, 4 loads still in flight.
    {
      u16* st0 = ho + (size_t)(bb + l4 * 4) * 512 + hb_i * 16 + l15;
      u16* st1 = st0 + 16 * 512;
      int tt2 = (tt + 2 < TCH) ? (tt + 2) : (TCH - 1);
      const u16* gaddr = gxblk + (size_t)tt2 * 8192;
      f32x4 g0, g1, g2, g3;
      asm volatile(
        "global_store_short %12, %4, off sc0 sc1\n\t"
        "global_store_short %12, %5, off offset:1024 sc0 sc1\n\t"
        "global_store_short %12, %6, off offset:2048 sc0 sc1\n\t"
        "global_store_short %12, %7, off offset:3072 sc0 sc1\n\t"
        "global_store_short %13, %8, off sc0 sc1\n\t"
        "global_store_short %13, %9, off offset:1024 sc0 sc1\n\t"
        "global_store_short %13, %10, off offset:2048 sc0 sc1\n\t"
        "global_store_short %13, %11, off offset:3072 sc0 sc1\n\t"
        "global_load_dwordx4 %0, %14, off\n\t"
        "global_load_dwordx4 %1, %14, off offset:16\n\t"
        "global_load_dwordx4 %2, %14, off offset:32\n\t"
        "global_load_dwordx4 %3, %14, off offset:48\n\t"
        "s_waitcnt vmcnt(4)"
        : "=&v"(g0), "=&v"(g1), "=&v"(g2), "=&v"(g3)
        : "v"(hvv[0][0]), "v"(hvv[0][1]), "v"(hvv[0][2]), "v"(hvv[0][3]),
          "v"(hvv[1][0]), "v"(hvv[1][1]), "v"(hvv[1][2]), "v"(hvv[1][3]),
          "v"(st0), "v"(st1), "v"(gaddr)
        : "memory");
      __syncthreads();
      if (tid == 0)
        __hip_atomic_store(myflag, target + 1, __ATOMIC_RELAXED, __HIP_MEMORY_SCOPE_AGENT);
      #pragma unroll
      for (int j = 0; j < 4; ++j) gxv4[j] = gxn4[j];
      gxn4[0] = __builtin_bit_cast(bf16x8, g0);
      gxn4[1] = __builtin_bit_cast(bf16x8, g1);
      gxn4[2] = __builtin_bit_cast(bf16x8, g2);
      gxn4[3] = __builtin_bit_cast(bf16x8, g3);
    }
  }
  #pragma unroll
  for (int mt = 0; mt < 2; ++mt)
    #pragma unroll
    for (int r = 0; r < 4; ++r) {
      int b = bb + mt * 16 + l4 * 4 + r;
      cbuf[((size_t)d * 128 + b) * 512 + hb_i * 16 + l15] = c2[mt][r];
    }
}

// ---------------- final: max over directions, from h history ----------------
__global__ void k_final(const u16* __restrict__ hb, float* __restrict__ out, int n) {
  int i = blockIdx.x * 256 + threadIdx.x;
  if (i >= n) return;
  int t = i >> 16, rem = i & 65535;
  int b = rem >> 9, j = rem & 511;
  const u16* s = hb + (size_t)(t + 1) * NSLOT + (size_t)b * 512 + j;
  float a = bf2f(s[0]);
  float bv = bf2f(s[HDIR]);
  out[i] = fmaxf(a, bv);
}

extern "C" void kernel_launch(void* const* d_in, const int* in_sizes, int n_in,
                              void* d_out, int out_size, void* d_ws, size_t ws_size,
                              hipStream_t stream) {
  (void)in_sizes; (void)n_in; (void)out_size; (void)ws_size;
  const int*   tokens = (const int*)d_in[0];
  const float* embedW = (const float*)d_in[1];
  const float* W_ih0  = (const float*)d_in[2];
  const float* W_hh0  = (const float*)d_in[3];
  const float* b_ih0  = (const float*)d_in[4];
  const float* b_hh0  = (const float*)d_in[5];
  const float* W_ih   = (const float*)d_in[6];
  const float* W_hh   = (const float*)d_in[7];
  const float* b_ih   = (const float*)d_in[8];
  const float* b_hh   = (const float*)d_in[9];

  char* ws = (char*)d_ws;
  size_t off = 0;
  auto alloc = [&](size_t bytes) { void* p = ws + off; off += (bytes + 255) & ~(size_t)255; return p; };
  float* biasC = (float*)alloc(20480ull * 4);             // [5][2][2048]
  u16*   hbuf  = (u16*)alloc((size_t)257 * NSLOT * 2);    // [257][2][128][512]  67.4MB
  u16*   gxA   = (u16*)alloc(16777216ull * 2);            // gx chunk A          33.5MB
  u16*   gxB   = (u16*)alloc(16777216ull * 2);            // gx chunk B          33.5MB
  float* cbuf  = (float*)alloc(131072ull * 4);            // [2][128][512]        0.5MB
  u32*   flags = (u32*)alloc(8192);
  // total ~135 MB (< 138 MB proven available)

  hipMemsetAsync(flags, 0, 8192, stream);
  k_bias<<<80, 256, 0, stream>>>(b_ih0, b_hh0, b_ih, b_hh, biasC);
  // prologue: layer-0 chunk-0 input GEMM (embedding mode) -> gxA
  k_gemm0<<<dim3(32, 32), 256, 0, stream>>>(embedW, tokens, W_ih0, biasC, gxA);

  u32 base = 0;
  for (int l = 0; l < 5; ++l) {
    const float* Whf_l = l ? (W_hh + (size_t)(l - 1) * 2097152) : W_hh0;
    for (int c = 0; c < 8; ++c) {
      int g = l * 8 + c;                       // global chunk index
      u16* gx_s = (g & 1) ? gxB : gxA;         // scan reads
      u16* gx_g = (g & 1) ? gxA : gxB;         // gemm writes next chunk
      int lg = (c < 7) ? l : l + 1;
      int cg = (c < 7) ? c + 1 : 0;
      int has_g = (lg <= 4);
      const float* Wif_g = (lg == 0) ? W_ih0 : (W_ih + (size_t)(lg - 1) * 4194304);
      const int* tok_g = (lg == 0) ? tokens : nullptr;
      int Kg = (lg == 0) ? 320 : 1024;
      k_fused<<<320, 256, 0, stream>>>(
          Whf_l, gx_s, hbuf, cbuf, flags, base, c * TCH, (l == 0 && c == 0) ? 1 : 0,
          embedW, tok_g, Wif_g, biasC + (size_t)lg * 4096, gx_g, Kg,
          has_g ? cg * TCH : -1);
      base += 64;
    }
  }
  k_final<<<65536, 256, 0, stream>>>(hbuf, (float*)d_out, 16777216);
}

// Round 8
// 10246.235 us; speedup vs baseline: 1.6711x; 1.0771x over previous
//
#include <hip/hip_runtime.h>
#include <stdint.h>

typedef unsigned short u16;
typedef unsigned int   u32;
typedef unsigned long long u64;
typedef short bf16x8 __attribute__((ext_vector_type(8)));
typedef float f32x4  __attribute__((ext_vector_type(4)));

static_assert(sizeof(bf16x8) == 16, "bf16x8 must be 16B");

#define LOG2E 1.4426950408889634f
#define TCH 32
#define NSLOT 131072   // u16 elems per hbuf time slot: 2 dirs * 128 * 512
#define HDIR  65536    // u16 elems per direction within a slot

__device__ __forceinline__ float bf2f(u16 u) { return __builtin_bit_cast(float, ((u32)u) << 16); }
__device__ __forceinline__ u16 f2bf(float f) {
  u32 x = __builtin_bit_cast(u32, f);
  return (u16)((x + 0x7fffu + ((x >> 16) & 1u)) >> 16);
}
__device__ __forceinline__ float sigm(float x) {
  return __builtin_amdgcn_rcpf(1.f + __builtin_amdgcn_exp2f(-LOG2E * x));
}
__device__ __forceinline__ float tanh_(float x) {
  return 1.f - 2.f * __builtin_amdgcn_rcpf(1.f + __builtin_amdgcn_exp2f(2.f * LOG2E * x));
}
__device__ __forceinline__ bf16x8 cvt8(const float* p) {
  bf16x8 r;
  #pragma unroll
  for (int j = 0; j < 8; ++j) r[j] = (short)f2bf(p[j]);
  return r;
}

// ---------------- prep ----------------
__global__ void k_bias(const float* __restrict__ bi0, const float* __restrict__ bh0,
                       const float* __restrict__ bi, const float* __restrict__ bh,
                       float* __restrict__ out) {
  int i = blockIdx.x * blockDim.x + threadIdx.x;
  if (i < 4096) out[i] = bi0[i] + bh0[i];
  else if (i < 20480) out[i] = bi[i - 4096] + bh[i - 4096];
}

// ---------------- GEMM tile (device): one 128x128 tile for (d, nt0, tt) ----------------
__device__ __forceinline__ void gemm_tile(
    u16* smem, const u16* hb, const float* emb, const int* tok,
    const float* Wif, const float* bias, u16* gx, int K, int t0,
    int d, int nt0, int tt)
{
  u16* As = smem;
  u16* Bs = smem + 8192;
  int* s_tok = (int*)(smem + 16384);
  int tid = threadIdx.x, lane = tid & 63, w = tid >> 6;
  int wm = w & 1, wn = w >> 1;
  int t = t0 + tt;
  if (tok && tid < 128) s_tok[tid] = tok[t * 128 + tid];
  __syncthreads();

  const float* Bbase = Wif + ((size_t)d * 2048 + nt0 * 128) * K;
  f32x4 acc[4][4];
  #pragma unroll
  for (int a = 0; a < 4; ++a)
    #pragma unroll
    for (int b = 0; b < 4; ++b) acc[a][b] = f32x4{0.f, 0.f, 0.f, 0.f};

  int nkt = K >> 6;
  for (int kt = 0; kt < nkt; ++kt) {
    #pragma unroll
    for (int i = 0; i < 4; ++i) {
      int s = tid + i * 256;
      int row = s >> 3, c = s & 7;
      int cs = c ^ (row & 7);
      bf16x8 va;
      if (tok) {
        va = cvt8(emb + (size_t)s_tok[row] * 320 + kt * 64 + c * 8);
      } else {
        int k = kt * 64 + c * 8;
        va = *(const bf16x8*)(hb + (size_t)(t + 1) * NSLOT + (size_t)(k >> 9) * HDIR
                              + (size_t)row * 512 + (k & 511));
      }
      bf16x8 vb = cvt8(Bbase + (size_t)row * K + kt * 64 + c * 8);
      *(bf16x8*)(&As[(row * 8 + cs) * 8]) = va;
      *(bf16x8*)(&Bs[(row * 8 + cs) * 8]) = vb;
    }
    __syncthreads();
    #pragma unroll
    for (int kk2 = 0; kk2 < 2; ++kk2) {
      int cl = kk2 * 4 + (lane >> 4);
      bf16x8 af[4], bfr[4];
      #pragma unroll
      for (int mt = 0; mt < 4; ++mt) {
        int row = wm * 64 + mt * 16 + (lane & 15);
        af[mt] = *(const bf16x8*)(&As[(row * 8 + (cl ^ (row & 7))) * 8]);
      }
      #pragma unroll
      for (int nt = 0; nt < 4; ++nt) {
        int row = wn * 64 + nt * 16 + (lane & 15);
        bfr[nt] = *(const bf16x8*)(&Bs[(row * 8 + (cl ^ (row & 7))) * 8]);
      }
      #pragma unroll
      for (int mt = 0; mt < 4; ++mt)
        #pragma unroll
        for (int nt = 0; nt < 4; ++nt)
          acc[mt][nt] = __builtin_amdgcn_mfma_f32_16x16x32_bf16(af[mt], bfr[nt], acc[mt][nt], 0, 0, 0);
    }
    __syncthreads();
  }
  #pragma unroll
  for (int nt = 0; nt < 4; ++nt) {
    int g = nt0 * 128 + wn * 64 + nt * 16 + (lane & 15);
    float bv = bias[d * 2048 + g];
    int q = g >> 9, hbb = (g >> 4) & 31, u = g & 15;
    size_t cb = (((size_t)d * 32 + hbb) * TCH + tt) * 8192;
    #pragma unroll
    for (int mt = 0; mt < 4; ++mt)
      #pragma unroll
      for (int r = 0; r < 4; ++r) {
        int b = wm * 64 + mt * 16 + (lane >> 4) * 4 + r;
        int ws2 = b >> 5, mts = (b >> 4) & 1, l4s = (b >> 2) & 3, rs = b & 3;
        gx[cb + (size_t)(ws2 * 64 + l4s * 16 + u) * 32 + mts * 16 + q * 4 + rs]
          = f2bf(acc[mt][nt][r] + bv);
      }
  }
}

// ---------------- prologue GEMM: layer 0 chunk 0 ----------------
__global__ __launch_bounds__(256) void k_gemm0(
    const float* __restrict__ emb, const int* __restrict__ tok,
    const float* __restrict__ Wif, const float* __restrict__ bias, u16* __restrict__ gx)
{
  __shared__ __align__(16) u16 smem[16640];
  int xt = blockIdx.x;
  gemm_tile(smem, nullptr, emb, tok, Wif, bias, gx, 320, 0, xt >> 4, xt & 15, blockIdx.y);
}

// ---- per-wave flag wait: flags line (64B) per (d,hb), word w = wave-w counter ----
// wave-group w only needs wave-w producers (h rows [32w,32w+32)) -> finer pipelining.
__device__ __forceinline__ void waitflags(const u32* fl, int lane, int w, u32 target) {
  const u32* p = fl + ((lane & 31) << 4) + w;
  u32 v;
  for (;;) {
    asm volatile("global_load_dword %0, %1, off sc0 sc1\n\ts_waitcnt vmcnt(0)"
                 : "=v"(v) : "v"(p) : "memory");
    if (__all((int)(v >= target))) break;
    __builtin_amdgcn_s_sleep(1);   // backoff: cut poll pressure on the coherent fabric
  }
}

// ---------------- fused kernel: blocks 0..63 scan chunk c; blocks 64..319 GEMM next ----------------
__global__ __launch_bounds__(256, 2) void k_fused(
    const float* __restrict__ Whf, const u16* __restrict__ gx_s,
    u16* __restrict__ hb, float* __restrict__ cbuf,
    u32* flags, u32 base, int t0, int hz,
    const float* __restrict__ emb, const int* __restrict__ tok_g,
    const float* __restrict__ Wif_g, const float* __restrict__ bias_g,
    u16* __restrict__ gx_g, int Kg, int t0g)
{
  __shared__ __align__(16) u16 smem[32768];
  int tid = threadIdx.x, lane = tid & 63, w = tid >> 6;

  if (blockIdx.x >= 64) {          // ---------- GEMM role ----------
    if (t0g < 0) return;
    #pragma unroll 1
    for (int i = 0; i < 4; ++i) {
      int tau = (blockIdx.x - 64) + i * 256;   // 0..1023
      int xt = tau & 31, tt = tau >> 5;
      gemm_tile(smem, hb, emb, tok_g, Wif_g, bias_g, gx_g, Kg, t0g, xt >> 4, xt & 15, tt);
      __syncthreads();
    }
    return;
  }

  // ---------- scan role ----------
  int d = blockIdx.x >> 5, hb_i = blockIdx.x & 31;
  const u32* fl = flags + d * 512;
  u32* myflag = flags + d * 512 + hb_i * 16 + w;   // this wave's flag word
  u16* WhL = smem;
  for (int i = tid; i < 64 * 512; i += 256) {
    int r = i >> 9, k = i & 511;
    int grow = (r >> 4) * 512 + hb_i * 16 + (r & 15);
    WhL[(r << 9) + (k ^ ((r & 7) << 3))] = f2bf(Whf[((size_t)d * 2048 + grow) * 512 + k]);
  }

  int bb = w * 32;
  int l15 = lane & 15, l4 = lane >> 4;
  float c2[2][4];
  if (t0 == 0) {
    #pragma unroll
    for (int mt = 0; mt < 2; ++mt)
      #pragma unroll
      for (int r = 0; r < 4; ++r) c2[mt][r] = 0.f;
  } else {
    #pragma unroll
    for (int mt = 0; mt < 2; ++mt)
      #pragma unroll
      for (int r = 0; r < 4; ++r) {
        int b = bb + mt * 16 + l4 * 4 + r;
        c2[mt][r] = cbuf[((size_t)d * 128 + b) * 512 + hb_i * 16 + l15];
      }
  }
  if (hz) {   // zero h(-1): slot 0, own columns (coherent stores)
    for (int i = tid; i < 512; i += 256) {
      int b = i >> 2, j = i & 3;
      u64* p = (u64*)(hb + (size_t)d * HDIR + (size_t)b * 512 + hb_i * 16) + j;
      __hip_atomic_store(p, 0ull, __ATOMIC_RELAXED, __HIP_MEMORY_SCOPE_AGENT);
    }
  }
  __syncthreads();                 // WhL staged + all zero-stores drained
  if (hz && lane == 0) {
    u32 iv = base + 1;
    asm volatile("global_store_dword %0, %1, off sc0 sc1" :: "v"(myflag), "v"(iv) : "memory");
  }
  int init1 = hz ? 1 : 0;
  __builtin_amdgcn_s_setprio(1);   // scan is the critical path

  const u16* gxblk = gx_s + ((size_t)d * 32 + hb_i) * TCH * 8192 + (size_t)tid * 32;
  bf16x8 gxv4[4], gxn4[4];
  #pragma unroll
  for (int j = 0; j < 4; ++j) gxv4[j] = *(const bf16x8*)(gxblk + j * 8);
  #pragma unroll
  for (int j = 0; j < 4; ++j) gxn4[j] = *(const bf16x8*)(gxblk + 8192 + j * 8);

  for (int tt = 0; tt < TCH; ++tt) {
    int t = t0 + tt;
    u32 target = base + (u32)tt + (u32)init1;
    if (!(tt == 0 && !init1)) waitflags(fl, lane, w, target);

    // h(t-1): 32x16B coherent loads, one vmcnt(0); =&v prevents addr/dest aliasing
    const u16* hp = hb + (size_t)t * NSLOT + (size_t)d * HDIR;
    const u16* hpA = hp + (size_t)(bb + l15) * 512 + l4 * 8;
    const u16* hpB = hp + (size_t)(bb + 16 + l15) * 512 + l4 * 8;
    f32x4 h0[16], h1[16];
    asm volatile(
      "global_load_dwordx4 %0, %8, off sc0 sc1\n\t"
      "global_load_dwordx4 %1, %8, off offset:64 sc0 sc1\n\t"
      "global_load_dwordx4 %2, %8, off offset:128 sc0 sc1\n\t"
      "global_load_dwordx4 %3, %8, off offset:192 sc0 sc1\n\t"
      "global_load_dwordx4 %4, %8, off offset:256 sc0 sc1\n\t"
      "global_load_dwordx4 %5, %8, off offset:320 sc0 sc1\n\t"
      "global_load_dwordx4 %6, %8, off offset:384 sc0 sc1\n\t"
      "global_load_dwordx4 %7, %8, off offset:448 sc0 sc1"
      : "=&v"(h0[0]), "=&v"(h0[1]), "=&v"(h0[2]), "=&v"(h0[3]),
        "=&v"(h0[4]), "=&v"(h0[5]), "=&v"(h0[6]), "=&v"(h0[7])
      : "v"(hpA) : "memory");
    asm volatile(
      "global_load_dwordx4 %0, %8, off offset:512 sc0 sc1\n\t"
      "global_load_dwordx4 %1, %8, off offset:576 sc0 sc1\n\t"
      "global_load_dwordx4 %2, %8, off offset:640 sc0 sc1\n\t"
      "global_load_dwordx4 %3, %8, off offset:704 sc0 sc1\n\t"
      "global_load_dwordx4 %4, %8, off offset:768 sc0 sc1\n\t"
      "global_load_dwordx4 %5, %8, off offset:832 sc0 sc1\n\t"
      "global_load_dwordx4 %6, %8, off offset:896 sc0 sc1\n\t"
      "global_load_dwordx4 %7, %8, off offset:960 sc0 sc1"
      : "=&v"(h0[8]), "=&v"(h0[9]), "=&v"(h0[10]), "=&v"(h0[11]),
        "=&v"(h0[12]), "=&v"(h0[13]), "=&v"(h0[14]), "=&v"(h0[15])
      : "v"(hpA) : "memory");
    asm volatile(
      "global_load_dwordx4 %0, %8, off sc0 sc1\n\t"
      "global_load_dwordx4 %1, %8, off offset:64 sc0 sc1\n\t"
      "global_load_dwordx4 %2, %8, off offset:128 sc0 sc1\n\t"
      "global_load_dwordx4 %3, %8, off offset:192 sc0 sc1\n\t"
      "global_load_dwordx4 %4, %8, off offset:256 sc0 sc1\n\t"
      "global_load_dwordx4 %5, %8, off offset:320 sc0 sc1\n\t"
      "global_load_dwordx4 %6, %8, off offset:384 sc0 sc1\n\t"
      "global_load_dwordx4 %7, %8, off offset:448 sc0 sc1"
      : "=&v"(h1[0]), "=&v"(h1[1]), "=&v"(h1[2]), "=&v"(h1[3]),
        "=&v"(h1[4]), "=&v"(h1[5]), "=&v"(h1[6]), "=&v"(h1[7])
      : "v"(hpB) : "memory");
    asm volatile(
      "global_load_dwordx4 %0, %8, off offset:512 sc0 sc1\n\t"
      "global_load_dwordx4 %1, %8, off offset:576 sc0 sc1\n\t"
      "global_load_dwordx4 %2, %8, off offset:640 sc0 sc1\n\t"
      "global_load_dwordx4 %3, %8, off offset:704 sc0 sc1\n\t"
      "global_load_dwordx4 %4, %8, off offset:768 sc0 sc1\n\t"
      "global_load_dwordx4 %5, %8, off offset:832 sc0 sc1\n\t"
      "global_load_dwordx4 %6, %8, off offset:896 sc0 sc1\n\t"
      "global_load_dwordx4 %7, %8, off offset:960 sc0 sc1\n\t"
      "s_waitcnt vmcnt(0)"
      : "=&v"(h1[8]), "=&v"(h1[9]), "=&v"(h1[10]), "=&v"(h1[11]),
        "=&v"(h1[12]), "=&v"(h1[13]), "=&v"(h1[14]), "=&v"(h1[15])
      : "v"(hpB) : "memory");
    __builtin_amdgcn_sched_barrier(0);

    f32x4 acc[2][4];
    #pragma unroll
    for (int mt = 0; mt < 2; ++mt)
      #pragma unroll
      for (int q = 0; q < 4; ++q) acc[mt][q] = f32x4{0.f, 0.f, 0.f, 0.f};
    #pragma unroll
    for (int kk = 0; kk < 16; ++kk) {
      int kbase = kk * 32 + l4 * 8;
      bf16x8 a0 = __builtin_bit_cast(bf16x8, h0[kk]);
      bf16x8 a1 = __builtin_bit_cast(bf16x8, h1[kk]);
      #pragma unroll
      for (int q = 0; q < 4; ++q) {
        int r = q * 16 + l15;
        bf16x8 bv = *(const bf16x8*)(&WhL[(r << 9) + (kbase ^ ((r & 7) << 3))]);
        acc[0][q] = __builtin_amdgcn_mfma_f32_16x16x32_bf16(a0, bv, acc[0][q], 0, 0, 0);
        acc[1][q] = __builtin_amdgcn_mfma_f32_16x16x32_bf16(a1, bv, acc[1][q], 0, 0, 0);
      }
    }
    u16* ho = hb + (size_t)(t + 1) * NSLOT + (size_t)d * HDIR;
    u32 hvv[2][4];
    #pragma unroll
    for (int mt = 0; mt < 2; ++mt)
      #pragma unroll
      for (int r = 0; r < 4; ++r) {
        float gi = acc[mt][0][r] + bf2f((u16)gxv4[mt * 2][r]);
        float gf = acc[mt][1][r] + bf2f((u16)gxv4[mt * 2][4 + r]);
        float gg = acc[mt][2][r] + bf2f((u16)gxv4[mt * 2 + 1][r]);
        float go = acc[mt][3][r] + bf2f((u16)gxv4[mt * 2 + 1][4 + r]);
        float cn = sigm(gf) * c2[mt][r] + sigm(gi) * tanh_(gg);
        float hn = sigm(go) * tanh_(cn);
        c2[mt][r] = cn;
        hvv[mt][r] = (u32)f2bf(hn);
      }
    // 8 coherent h-stores + 4 gx(t+2) loads; vmcnt(4) = stores done (loads flying);
    // then THIS WAVE's flag goes out immediately — no block barrier.
    {
      u16* st0 = ho + (size_t)(bb + l4 * 4) * 512 + hb_i * 16 + l15;
      u16* st1 = st0 + 16 * 512;
      int tt2 = (tt + 2 < TCH) ? (tt + 2) : (TCH - 1);
      const u16* gaddr = gxblk + (size_t)tt2 * 8192;
      u32 fv = target + 1;
      f32x4 g0, g1, g2, g3;
      asm volatile(
        "global_store_short %13, %4, off sc0 sc1\n\t"
        "global_store_short %13, %5, off offset:1024 sc0 sc1\n\t"
        "global_store_short %13, %6, off offset:2048 sc0 sc1\n\t"
        "global_store_short %13, %7, off offset:3072 sc0 sc1\n\t"
        "global_store_short %14, %8, off sc0 sc1\n\t"
        "global_store_short %14, %9, off offset:1024 sc0 sc1\n\t"
        "global_store_short %14, %10, off offset:2048 sc0 sc1\n\t"
        "global_store_short %14, %11, off offset:3072 sc0 sc1\n\t"
        "global_load_dwordx4 %0, %15, off\n\t"
        "global_load_dwordx4 %1, %15, off offset:16\n\t"
        "global_load_dwordx4 %2, %15, off offset:32\n\t"
        "global_load_dwordx4 %3, %15, off offset:48\n\t"
        "s_waitcnt vmcnt(4)\n\t"
        "global_store_dword %16, %12, off sc0 sc1"
        : "=&v"(g0), "=&v"(g1), "=&v"(g2), "=&v"(g3)
        : "v"(hvv[0][0]), "v"(hvv[0][1]), "v"(hvv[0][2]), "v"(hvv[0][3]),
          "v"(hvv[1][0]), "v"(hvv[1][1]), "v"(hvv[1][2]), "v"(hvv[1][3]),
          "v"(fv), "v"(st0), "v"(st1), "v"(gaddr), "v"(myflag)
        : "memory");
      #pragma unroll
      for (int j = 0; j < 4; ++j) gxv4[j] = gxn4[j];
      gxn4[0] = __builtin_bit_cast(bf16x8, g0);
      gxn4[1] = __builtin_bit_cast(bf16x8, g1);
      gxn4[2] = __builtin_bit_cast(bf16x8, g2);
      gxn4[3] = __builtin_bit_cast(bf16x8, g3);
    }
  }
  #pragma unroll
  for (int mt = 0; mt < 2; ++mt)
    #pragma unroll
    for (int r = 0; r < 4; ++r) {
      int b = bb + mt * 16 + l4 * 4 + r;
      cbuf[((size_t)d * 128 + b) * 512 + hb_i * 16 + l15] = c2[mt][r];
    }
}

// ---------------- final: max over directions, from h history ----------------
__global__ void k_final(const u16* __restrict__ hb, float* __restrict__ out, int n) {
  int i = blockIdx.x * 256 + threadIdx.x;
  if (i >= n) return;
  int t = i >> 16, rem = i & 65535;
  int b = rem >> 9, j = rem & 511;
  const u16* s = hb + (size_t)(t + 1) * NSLOT + (size_t)b * 512 + j;
  float a = bf2f(s[0]);
  float bv = bf2f(s[HDIR]);
  out[i] = fmaxf(a, bv);
}

extern "C" void kernel_launch(void* const* d_in, const int* in_sizes, int n_in,
                              void* d_out, int out_size, void* d_ws, size_t ws_size,
                              hipStream_t stream) {
  (void)in_sizes; (void)n_in; (void)out_size; (void)ws_size;
  const int*   tokens = (const int*)d_in[0];
  const float* embedW = (const float*)d_in[1];
  const float* W_ih0  = (const float*)d_in[2];
  const float* W_hh0  = (const float*)d_in[3];
  const float* b_ih0  = (const float*)d_in[4];
  const float* b_hh0  = (const float*)d_in[5];
  const float* W_ih   = (const float*)d_in[6];
  const float* W_hh   = (const float*)d_in[7];
  const float* b_ih   = (const float*)d_in[8];
  const float* b_hh   = (const float*)d_in[9];

  char* ws = (char*)d_ws;
  size_t off = 0;
  auto alloc = [&](size_t bytes) { void* p = ws + off; off += (bytes + 255) & ~(size_t)255; return p; };
  float* biasC = (float*)alloc(20480ull * 4);             // [5][2][2048]
  u16*   hbuf  = (u16*)alloc((size_t)257 * NSLOT * 2);    // [257][2][128][512]  67.4MB
  u16*   gxA   = (u16*)alloc(16777216ull * 2);            // gx chunk A          33.5MB
  u16*   gxB   = (u16*)alloc(16777216ull * 2);            // gx chunk B          33.5MB
  float* cbuf  = (float*)alloc(131072ull * 4);            // [2][128][512]        0.5MB
  u32*   flags = (u32*)alloc(8192);                       // [2][32] lines x 4 wave-words
  // total ~135 MB

  hipMemsetAsync(flags, 0, 8192, stream);
  k_bias<<<80, 256, 0, stream>>>(b_ih0, b_hh0, b_ih, b_hh, biasC);
  k_gemm0<<<dim3(32, 32), 256, 0, stream>>>(embedW, tokens, W_ih0, biasC, gxA);

  u32 base = 0;
  for (int l = 0; l < 5; ++l) {
    const float* Whf_l = l ? (W_hh + (size_t)(l - 1) * 2097152) : W_hh0;
    for (int c = 0; c < 8; ++c) {
      int g = l * 8 + c;
      u16* gx_s = (g & 1) ? gxB : gxA;
      u16* gx_g = (g & 1) ? gxA : gxB;
      int lg = (c < 7) ? l : l + 1;
      int cg = (c < 7) ? c + 1 : 0;
      int has_g = (lg <= 4);
      const float* Wif_g = (lg == 0) ? W_ih0 : (W_ih + (size_t)(lg - 1) * 4194304);
      const int* tok_g = (lg == 0) ? tokens : nullptr;
      int Kg = (lg == 0) ? 320 : 1024;
      k_fused<<<320, 256, 0, stream>>>(
          Whf_l, gx_s, hbuf, cbuf, flags, base, c * TCH, (l == 0 && c == 0) ? 1 : 0,
          embedW, tok_g, Wif_g, biasC + (size_t)lg * 4096, gx_g, Kg,
          has_g ? cg * TCH : -1);
      base += 40;   // > max per-chunk flag increment (33), keeps targets monotone
    }
  }
  k_final<<<65536, 256, 0, stream>>>(hbuf, (float*)d_out, 16777216);
}

// Round 10
// 9650.131 us; speedup vs baseline: 1.7744x; 1.0618x over previous
//
#include <hip/hip_runtime.h>
#include <stdint.h>

typedef unsigned short u16;
typedef unsigned int   u32;
typedef unsigned long long u64;
typedef short bf16x8 __attribute__((ext_vector_type(8)));
typedef float f32x4  __attribute__((ext_vector_type(4)));

static_assert(sizeof(bf16x8) == 16, "bf16x8 must be 16B");

#define LOG2E 1.4426950408889634f
#define TCH 8          // timesteps per cell (chunk)
#define NSLOT 131072   // u16 per h time slot: 2 dirs * 128 * 512
#define HDIR  65536
#define GXCELL 4194304ull   // u16 per gx buffer: 2*32*8*8192

__device__ __forceinline__ float bf2f(u16 u) { return __builtin_bit_cast(float, ((u32)u) << 16); }
__device__ __forceinline__ u16 f2bf(float f) {
  u32 x = __builtin_bit_cast(u32, f);
  return (u16)((x + 0x7fffu + ((x >> 16) & 1u)) >> 16);
}
__device__ __forceinline__ float sigm(float x) {
  return __builtin_amdgcn_rcpf(1.f + __builtin_amdgcn_exp2f(-LOG2E * x));
}
__device__ __forceinline__ float tanh_(float x) {
  return 1.f - 2.f * __builtin_amdgcn_rcpf(1.f + __builtin_amdgcn_exp2f(2.f * LOG2E * x));
}
__device__ __forceinline__ bf16x8 cvt8(const float* p) {
  bf16x8 r;
  #pragma unroll
  for (int j = 0; j < 8; ++j) r[j] = (short)f2bf(p[j]);
  return r;
}
// order-preserving float<->u32 encode for atomic max (no NaN inputs)
__device__ __forceinline__ u32 encf(float f) {
  u32 b = __builtin_bit_cast(u32, f);
  return (b & 0x80000000u) ? ~b : (b | 0x80000000u);
}

// ---------------- prep ----------------
__global__ void k_bias(const float* __restrict__ bi0, const float* __restrict__ bh0,
                       const float* __restrict__ bi, const float* __restrict__ bh,
                       float* __restrict__ out) {
  int i = blockIdx.x * blockDim.x + threadIdx.x;
  if (i < 4096) out[i] = bi0[i] + bh0[i];
  else if (i < 20480) out[i] = bi[i - 4096] + bh[i - 4096];
}

// ---------------- GEMM tile: one 128x128 tile for cell (lg,cg), step tt, (d,nt0) ----------------
__device__ __forceinline__ void gemm_tile(
    u16* smem, const u16* hbPrev, const float* emb, const int* tok,
    const float* Wif, const float* bias, u16* gx, int K,
    int c, int tt, int d, int nt0)
{
  u16* As = smem;
  u16* Bs = smem + 8192;
  int* s_tok = (int*)(smem + 16384);
  int tid = threadIdx.x, lane = tid & 63, w = tid >> 6;
  int wm = w & 1, wn = w >> 1;
  int t = c * TCH + tt;
  if (tok && tid < 128) s_tok[tid] = tok[t * 128 + tid];
  __syncthreads();

  const float* Bbase = Wif + ((size_t)d * 2048 + nt0 * 128) * K;
  int slot = (t + 1) & 15;
  f32x4 acc[4][4];
  #pragma unroll
  for (int a = 0; a < 4; ++a)
    #pragma unroll
    for (int b = 0; b < 4; ++b) acc[a][b] = f32x4{0.f, 0.f, 0.f, 0.f};

  int nkt = K >> 6;
  for (int kt = 0; kt < nkt; ++kt) {
    #pragma unroll
    for (int i = 0; i < 4; ++i) {
      int s = tid + i * 256;
      int row = s >> 3, cc = s & 7;
      int cs = cc ^ (row & 7);
      bf16x8 va;
      if (tok) {
        va = cvt8(emb + (size_t)s_tok[row] * 320 + kt * 64 + cc * 8);
      } else {
        int k = kt * 64 + cc * 8;
        va = *(const bf16x8*)(hbPrev + (size_t)slot * NSLOT + (size_t)(k >> 9) * HDIR
                              + (size_t)row * 512 + (k & 511));
      }
      bf16x8 vb = cvt8(Bbase + (size_t)row * K + kt * 64 + cc * 8);
      *(bf16x8*)(&As[(row * 8 + cs) * 8]) = va;
      *(bf16x8*)(&Bs[(row * 8 + cs) * 8]) = vb;
    }
    __syncthreads();
    #pragma unroll
    for (int kk2 = 0; kk2 < 2; ++kk2) {
      int cl = kk2 * 4 + (lane >> 4);
      bf16x8 af[4], bfr[4];
      #pragma unroll
      for (int mt = 0; mt < 4; ++mt) {
        int row = wm * 64 + mt * 16 + (lane & 15);
        af[mt] = *(const bf16x8*)(&As[(row * 8 + (cl ^ (row & 7))) * 8]);
      }
      #pragma unroll
      for (int nt = 0; nt < 4; ++nt) {
        int row = wn * 64 + nt * 16 + (lane & 15);
        bfr[nt] = *(const bf16x8*)(&Bs[(row * 8 + (cl ^ (row & 7))) * 8]);
      }
      #pragma unroll
      for (int mt = 0; mt < 4; ++mt)
        #pragma unroll
        for (int nt = 0; nt < 4; ++nt)
          acc[mt][nt] = __builtin_amdgcn_mfma_f32_16x16x32_bf16(af[mt], bfr[nt], acc[mt][nt], 0, 0, 0);
    }
    __syncthreads();
  }
  #pragma unroll
  for (int nt = 0; nt < 4; ++nt) {
    int g = nt0 * 128 + wn * 64 + nt * 16 + (lane & 15);
    float bv = bias[d * 2048 + g];
    int q = g >> 9, hbb = (g >> 4) & 31, u = g & 15;
    size_t cb = (((size_t)d * 32 + hbb) * TCH + tt) * 8192;
    #pragma unroll
    for (int mt = 0; mt < 4; ++mt)
      #pragma unroll
      for (int r = 0; r < 4; ++r) {
        int b = wm * 64 + mt * 16 + (lane >> 4) * 4 + r;
        int ws2 = b >> 5, mts = (b >> 4) & 1, l4s = (b >> 2) & 3, rs = b & 3;
        gx[cb + (size_t)(ws2 * 64 + l4s * 16 + u) * 32 + mts * 16 + q * 4 + rs]
          = f2bf(acc[mt][nt][r] + bv);
      }
  }
}

// ---------------- prologue GEMM: cell (0,0) ----------------
__global__ __launch_bounds__(256) void k_gemm0(
    const float* __restrict__ emb, const int* __restrict__ tok,
    const float* __restrict__ Wif, const float* __restrict__ bias, u16* __restrict__ gx)
{
  __shared__ __align__(16) u16 smem[16640];
  int xt = blockIdx.x;
  gemm_tile(smem, nullptr, emb, tok, Wif, bias, gx, 320, 0, blockIdx.y, xt >> 4, xt & 15);
}

// ---- scan wave-flag wait (r8-proven MALL transport): lane<32 polls word w of 32 lines ----
__device__ __forceinline__ void waitflags(const u32* fl, int lane, int w, u32 target) {
  const u32* p = fl + ((lane & 31) << 4) + w;
  for (;;) {
    u32 v;
    asm volatile("global_load_dword %0, %1, off sc0 sc1\n\ts_waitcnt vmcnt(0)"
                 : "=v"(v) : "v"(p) : "memory");
    if (__all((int)(v >= target))) break;
    __builtin_amdgcn_s_sleep(1);
  }
}
// ---- GEMM wait: all 4 wave-words of all 64 lines (both dirs) of producer layer ----
__device__ __forceinline__ void wait_all(const u32* flp, int lane, u32 target) {
  const u32* p = flp + lane * 16;
  for (;;) {
    f32x4 v4;
    asm volatile("global_load_dwordx4 %0, %1, off sc0 sc1\n\ts_waitcnt vmcnt(0)"
                 : "=v"(v4) : "v"(p) : "memory");
    u32 m0 = __builtin_bit_cast(u32, v4[0]), m1 = __builtin_bit_cast(u32, v4[1]);
    u32 m2 = __builtin_bit_cast(u32, v4[2]), m3 = __builtin_bit_cast(u32, v4[3]);
    u32 mn = m0 < m1 ? m0 : m1; mn = mn < m2 ? mn : m2; mn = mn < m3 ? mn : m3;
    if (__all((int)(mn >= target))) break;
    __builtin_amdgcn_s_sleep(2);
  }
}

#define HB8A(P, D) \
    asm volatile( \
      "global_load_dwordx4 %0, %8, off sc0 sc1\n\t" \
      "global_load_dwordx4 %1, %8, off offset:64 sc0 sc1\n\t" \
      "global_load_dwordx4 %2, %8, off offset:128 sc0 sc1\n\t" \
      "global_load_dwordx4 %3, %8, off offset:192 sc0 sc1\n\t" \
      "global_load_dwordx4 %4, %8, off offset:256 sc0 sc1\n\t" \
      "global_load_dwordx4 %5, %8, off offset:320 sc0 sc1\n\t" \
      "global_load_dwordx4 %6, %8, off offset:384 sc0 sc1\n\t" \
      "global_load_dwordx4 %7, %8, off offset:448 sc0 sc1" \
      : "=&v"(D[0]), "=&v"(D[1]), "=&v"(D[2]), "=&v"(D[3]), \
        "=&v"(D[4]), "=&v"(D[5]), "=&v"(D[6]), "=&v"(D[7]) \
      : "v"(P) : "memory")
#define HB8B(P, D) \
    asm volatile( \
      "global_load_dwordx4 %0, %8, off offset:512 sc0 sc1\n\t" \
      "global_load_dwordx4 %1, %8, off offset:576 sc0 sc1\n\t" \
      "global_load_dwordx4 %2, %8, off offset:640 sc0 sc1\n\t" \
      "global_load_dwordx4 %3, %8, off offset:704 sc0 sc1\n\t" \
      "global_load_dwordx4 %4, %8, off offset:768 sc0 sc1\n\t" \
      "global_load_dwordx4 %5, %8, off offset:832 sc0 sc1\n\t" \
      "global_load_dwordx4 %6, %8, off offset:896 sc0 sc1\n\t" \
      "global_load_dwordx4 %7, %8, off offset:960 sc0 sc1" \
      : "=&v"(D[8]), "=&v"(D[9]), "=&v"(D[10]), "=&v"(D[11]), \
        "=&v"(D[12]), "=&v"(D[13]), "=&v"(D[14]), "=&v"(D[15]) \
      : "v"(P) : "memory")

#define STPF_BODY(FLAGOPS) \
      asm volatile( \
        "global_store_short %13, %4, off sc0 sc1\n\t" \
        "global_store_short %13, %5, off offset:1024 sc0 sc1\n\t" \
        "global_store_short %13, %6, off offset:2048 sc0 sc1\n\t" \
        "global_store_short %13, %7, off offset:3072 sc0 sc1\n\t" \
        "global_store_short %14, %8, off sc0 sc1\n\t" \
        "global_store_short %14, %9, off offset:1024 sc0 sc1\n\t" \
        "global_store_short %14, %10, off offset:2048 sc0 sc1\n\t" \
        "global_store_short %14, %11, off offset:3072 sc0 sc1\n\t" \
        "global_load_dwordx4 %0, %15, off\n\t" \
        "global_load_dwordx4 %1, %15, off offset:16\n\t" \
        "global_load_dwordx4 %2, %15, off offset:32\n\t" \
        "global_load_dwordx4 %3, %15, off offset:48\n\t" \
        "s_waitcnt vmcnt(4)\n\t" \
        FLAGOPS \
        : "=&v"(g0), "=&v"(g1), "=&v"(g2), "=&v"(g3) \
        : "v"(hvv[0][0]), "v"(hvv[0][1]), "v"(hvv[0][2]), "v"(hvv[0][3]), \
          "v"(hvv[1][0]), "v"(hvv[1][1]), "v"(hvv[1][2]), "v"(hvv[1][3]), \
          "v"(fv), "v"(st0), "v"(st1), "v"(gaddr), "v"(myflag) \
        : "memory")

// ---------------- diagonal-wavefront kernel ----------------
// launch g: scan cells (l, g-l) for l in [max(0,g-31), min(4,g)]; GEMM preps diagonal g+1.
__global__ __launch_bounds__(256, 2) void k_wave(
    int g,
    const float* __restrict__ W_hh0, const float* __restrict__ W_hh,
    const float* __restrict__ W_ih0, const float* __restrict__ W_ih,
    const float* __restrict__ biasC, const float* __restrict__ emb,
    const int* __restrict__ tok,
    u16* __restrict__ hbuf, u16* __restrict__ gxb, float* __restrict__ cbuf,
    u32* __restrict__ outU, u32* __restrict__ flags)
{
  __shared__ __align__(16) u16 smem[32768];
  int tid = threadIdx.x, lane = tid & 63, w = tid >> 6;
  int bx = blockIdx.x;
  int llo_s = (g - 31 > 0) ? (g - 31) : 0;
  int lhi_s = (g < 4) ? g : 4;
  int nscan = lhi_s - llo_s + 1;

  if (bx >= 64 * nscan) {          // ---------- GEMM role: prepare diagonal g+1 ----------
    int D = g + 1;
    if (D > 35) return;
    int llo = (D - 31 > 0) ? (D - 31) : 0;
    int lhi = (D < 4) ? D : 4;
    int ncell = lhi - llo + 1;
    int J = ncell * 256;
    int gid = bx - 64 * nscan, NG = 512 - 64 * nscan;
    #pragma unroll 1
    for (int j = gid; j < J; j += NG) {
      int tt = j / (ncell * 32);
      int rem = j - tt * (ncell * 32);
      int ci = rem >> 5, dnt = rem & 31;
      int lg = llo + ci, cg = D - lg;
      const float* Wif = lg ? (W_ih + (size_t)(lg - 1) * 4194304) : W_ih0;
      int K = lg ? 1024 : 320;
      const int* tokp = lg ? nullptr : tok;
      const u16* hbPrev = lg ? (hbuf + (size_t)(lg - 1) * 16 * NSLOT) : nullptr;
      u16* gxd = gxb + ((size_t)(lg * 2 + (cg & 1))) * GXCELL;
      if (lg > 0 && w == 0)       // gate on same-launch producer scan (layer lg-1, chunk cg)
        wait_all(flags + (size_t)(lg - 1) * 1024, lane, 40u * cg + 2u + (u32)tt);
      gemm_tile(smem, hbPrev, emb, tokp, Wif, biasC + (size_t)lg * 4096,
                gxd, K, cg, tt, dnt >> 4, dnt & 15);
      __syncthreads();
    }
    return;
  }

  // ---------- scan role ----------
  int ci = bx >> 6, within = bx & 63;
  int l = llo_s + ci, c = g - l;
  int d = within >> 5, hb_i = within & 31;
  const float* Whf = l ? (W_hh + (size_t)(l - 1) * 2097152) : W_hh0;
  u16* hbL = hbuf + (size_t)l * 16 * NSLOT;
  float* cbL = cbuf + (size_t)l * 131072;
  const u16* gxs = gxb + ((size_t)(l * 2 + (c & 1))) * GXCELL;
  u32* fl = flags + (size_t)l * 1024 + d * 512;
  u32* myflag = fl + hb_i * 16 + w;
  u32 base = 40u * (u32)c;

  u16* WhL = smem;
  for (int i = tid; i < 64 * 512; i += 256) {
    int r = i >> 9, k = i & 511;
    int grow = (r >> 4) * 512 + hb_i * 16 + (r & 15);
    WhL[(r << 9) + (k ^ ((r & 7) << 3))] = f2bf(Whf[((size_t)d * 2048 + grow) * 512 + k]);
  }

  int bb = w * 32;
  int l15 = lane & 15, l4 = lane >> 4;
  float c2[2][4];
  if (c == 0) {
    #pragma unroll
    for (int mt = 0; mt < 2; ++mt)
      #pragma unroll
      for (int r = 0; r < 4; ++r) c2[mt][r] = 0.f;
    for (int i = tid; i < 512; i += 256) {      // zero h(-1): slot 0, own cols
      int b = i >> 2, j = i & 3;
      u64* p = (u64*)(hbL + (size_t)d * HDIR + (size_t)b * 512 + hb_i * 16) + j;
      __hip_atomic_store(p, 0ull, __ATOMIC_RELAXED, __HIP_MEMORY_SCOPE_AGENT);
    }
    __syncthreads();                            // zeros + WhL drained
    if (lane == 0) {
      u32 iv = base + 1;
      asm volatile("global_store_dword %0, %1, off sc0 sc1" :: "v"(myflag), "v"(iv) : "memory");
    }
    waitflags(fl, lane, w, base + 1);           // rendezvous: zeros visible
  } else {
    #pragma unroll
    for (int mt = 0; mt < 2; ++mt)
      #pragma unroll
      for (int r = 0; r < 4; ++r) {
        int b = bb + mt * 16 + l4 * 4 + r;
        c2[mt][r] = cbL[((size_t)d * 128 + b) * 512 + hb_i * 16 + l15];
      }
    __syncthreads();                            // WhL staged
  }
  __builtin_amdgcn_s_setprio(1);

  const u16* gxblk = gxs + ((size_t)(d * 32 + hb_i) * TCH) * 8192 + (size_t)tid * 32;
  bf16x8 gxv4[4], gxn4[4];
  #pragma unroll
  for (int j = 0; j < 4; ++j) gxv4[j] = *(const bf16x8*)(gxblk + j * 8);
  #pragma unroll
  for (int j = 0; j < 4; ++j) gxn4[j] = *(const bf16x8*)(gxblk + 8192 + j * 8);

  #pragma unroll 1
  for (int tt = 0; tt < TCH; ++tt) {
    int t = c * TCH + tt;
    if (tt > 0) waitflags(fl, lane, w, base + 1 + (u32)tt);

    const u16* hp = hbL + (size_t)(t & 15) * NSLOT + (size_t)d * HDIR;
    const u16* hpA = hp + (size_t)(bb + l15) * 512 + l4 * 8;
    const u16* hpB = hp + (size_t)(bb + 16 + l15) * 512 + l4 * 8;
    f32x4 h0[16], h1[16];
    HB8A(hpA, h0); HB8B(hpA, h0);
    HB8A(hpB, h1); HB8B(hpB, h1);
    asm volatile("s_waitcnt vmcnt(0)" ::: "memory");
    __builtin_amdgcn_sched_barrier(0);

    f32x4 acc[2][4];
    #pragma unroll
    for (int mt = 0; mt < 2; ++mt)
      #pragma unroll
      for (int q = 0; q < 4; ++q) acc[mt][q] = f32x4{0.f, 0.f, 0.f, 0.f};
    #pragma unroll
    for (int kk = 0; kk < 16; ++kk) {
      int kbase = kk * 32 + l4 * 8;
      bf16x8 a0 = __builtin_bit_cast(bf16x8, h0[kk]);
      bf16x8 a1 = __builtin_bit_cast(bf16x8, h1[kk]);
      #pragma unroll
      for (int q = 0; q < 4; ++q) {
        int r = q * 16 + l15;
        bf16x8 bv = *(const bf16x8*)(&WhL[(r << 9) + (kbase ^ ((r & 7) << 3))]);
        acc[0][q] = __builtin_amdgcn_mfma_f32_16x16x32_bf16(a0, bv, acc[0][q], 0, 0, 0);
        acc[1][q] = __builtin_amdgcn_mfma_f32_16x16x32_bf16(a1, bv, acc[1][q], 0, 0, 0);
      }
    }
    u16* ho = hbL + (size_t)((t + 1) & 15) * NSLOT + (size_t)d * HDIR;
    u32 hvv[2][4];
    float hnf[2][4];
    #pragma unroll
    for (int mt = 0; mt < 2; ++mt)
      #pragma unroll
      for (int r = 0; r < 4; ++r) {
        float gi = acc[mt][0][r] + bf2f((u16)gxv4[mt * 2][r]);
        float gf = acc[mt][1][r] + bf2f((u16)gxv4[mt * 2][4 + r]);
        float gg = acc[mt][2][r] + bf2f((u16)gxv4[mt * 2 + 1][r]);
        float go = acc[mt][3][r] + bf2f((u16)gxv4[mt * 2 + 1][4 + r]);
        float cn = sigm(gf) * c2[mt][r] + sigm(gi) * tanh_(gg);
        float hn = sigm(go) * tanh_(cn);
        c2[mt][r] = cn;
        hnf[mt][r] = hn;
        hvv[mt][r] = (u32)f2bf(hn);
      }
    {
      u16* st0 = ho + (size_t)(bb + l4 * 4) * 512 + hb_i * 16 + l15;
      u16* st1 = st0 + 16 * 512;
      int tt2 = (tt + 2 < TCH) ? (tt + 2) : (TCH - 1);
      const u16* gaddr = gxblk + (size_t)tt2 * 8192;
      u32 fv = base + 2 + (u32)tt;
      f32x4 g0, g1, g2, g3;
      if (lane == 0) { STPF_BODY("global_store_dword %16, %12, off sc0 sc1"); }
      else          { STPF_BODY("s_nop 0"); }
      if (l == 4) {   // output: encoded atomic max over directions, off critical path
        #pragma unroll
        for (int mt = 0; mt < 2; ++mt)
          #pragma unroll
          for (int r = 0; r < 4; ++r) {
            int b = bb + mt * 16 + l4 * 4 + r;
            atomicMax(&outU[((size_t)t * 128 + b) * 512 + hb_i * 16 + l15], encf(hnf[mt][r]));
          }
      }
      #pragma unroll
      for (int j = 0; j < 4; ++j) gxv4[j] = gxn4[j];
      gxn4[0] = __builtin_bit_cast(bf16x8, g0);
      gxn4[1] = __builtin_bit_cast(bf16x8, g1);
      gxn4[2] = __builtin_bit_cast(bf16x8, g2);
      gxn4[3] = __builtin_bit_cast(bf16x8, g3);
    }
  }
  #pragma unroll
  for (int mt = 0; mt < 2; ++mt)
    #pragma unroll
    for (int r = 0; r < 4; ++r) {
      int b = bb + mt * 16 + l4 * 4 + r;
      cbL[((size_t)d * 128 + b) * 512 + hb_i * 16 + l15] = c2[mt][r];
    }
}

// ---------------- decode encoded max back to float, in place ----------------
__global__ void k_decode(u32* __restrict__ p, int n) {
  int i = blockIdx.x * 256 + threadIdx.x;
  if (i >= n) return;
  u32 u = p[i];
  u32 b = (u & 0x80000000u) ? (u ^ 0x80000000u) : ~u;
  p[i] = b;
}

extern "C" void kernel_launch(void* const* d_in, const int* in_sizes, int n_in,
                              void* d_out, int out_size, void* d_ws, size_t ws_size,
                              hipStream_t stream) {
  (void)in_sizes; (void)n_in; (void)out_size; (void)ws_size;
  const int*   tokens = (const int*)d_in[0];
  const float* embedW = (const float*)d_in[1];
  const float* W_ih0  = (const float*)d_in[2];
  const float* W_hh0  = (const float*)d_in[3];
  const float* b_ih0  = (const float*)d_in[4];
  const float* b_hh0  = (const float*)d_in[5];
  const float* W_ih   = (const float*)d_in[6];
  const float* W_hh   = (const float*)d_in[7];
  const float* b_ih   = (const float*)d_in[8];
  const float* b_hh   = (const float*)d_in[9];

  char* ws = (char*)d_ws;
  size_t off = 0;
  auto alloc = [&](size_t bytes) { void* p = ws + off; off += (bytes + 255) & ~(size_t)255; return p; };
  float* biasC = (float*)alloc(20480ull * 4);                  //  0.08 MB
  u16*   hbuf  = (u16*)alloc((size_t)5 * 16 * NSLOT * 2);      // 21.0 MB  [5][16][2][128][512]
  u16*   gxb   = (u16*)alloc((size_t)10 * GXCELL * 2);         // 83.9 MB  [5][2 parity]
  float* cbuf  = (float*)alloc((size_t)5 * 131072 * 4);        //  2.6 MB
  u32*   flags = (u32*)alloc(32768);                           //  [5][2][32 lines x 16]
  // total ~107.6 MB (< 135 MB proven)

  hipMemsetAsync(flags, 0, 32768, stream);
  hipMemsetAsync(d_out, 0, (size_t)16777216 * 4, stream);      // atomic-max identity (enc 0)
  k_bias<<<80, 256, 0, stream>>>(b_ih0, b_hh0, b_ih, b_hh, biasC);
  // prologue: cell (0,0) gates from embedding -> gx[0][parity 0]
  k_gemm0<<<dim3(32, TCH), 256, 0, stream>>>(embedW, tokens, W_ih0, biasC, gxb);

  for (int g = 0; g < 36; ++g) {
    k_wave<<<512, 256, 0, stream>>>(g, W_hh0, W_hh, W_ih0, W_ih, biasC,
                                    embedW, tokens, hbuf, gxb, cbuf,
                                    (u32*)d_out, flags);
  }
  k_decode<<<65536, 256, 0, stream>>>((u32*)d_out, 16777216);
}